// Round 17
// baseline (1377.140 us; speedup 1.0000x reference)
//
#include <hip/hip_runtime.h>
#include <hip/hip_bf16.h>
#include <math.h>

#define B_    4096
#define V_    9
#define N_    (B_*V_)          // 36864 nodes
#define EK_   (B_*V_*(V_-1))   // 294912 kept edges
#define TPB   512              // 1024-thr blocks pin VGPR=64 (r13-r15); 512+arg2=2 -> 128

typedef unsigned short ushort_t;

__device__ __forceinline__ float b2f(ushort_t u) {
    union { unsigned int i; float f; } x; x.i = ((unsigned int)u) << 16; return x.f;
}
__device__ __forceinline__ ushort_t f2b(float f) {
    union { float f; unsigned int i; } x; x.f = f;
    unsigned int r = x.i + 0x7FFFu + ((x.i >> 16) & 1u);
    return (ushort_t)(r >> 16);
}

// ---------------------------------------------------------------------------
// Batched GEMM for the MLP head: out[M,Nc] = act(A[M,K] @ W[K,Nc] + bias)
// ---------------------------------------------------------------------------
__global__ __launch_bounds__(256) void gemm_act_kernel(
    const float* __restrict__ A, const float* __restrict__ W,
    const float* __restrict__ bias, float* __restrict__ out,
    int K, int Nc, int act)
{
    __shared__ float As[8 * 512];
    const int row0 = blockIdx.x * 8;
    const int tid  = threadIdx.x;

    for (int idx = tid; idx < 8 * K; idx += 256)
        As[idx] = A[row0 * K + idx];
    __syncthreads();

    const int total = 8 * Nc;
    for (int idx = tid; idx < total; idx += 256) {
        int r = idx / Nc;
        int n = idx - r * Nc;
        float acc = bias[n];
        const float* a = &As[r * K];
        for (int k = 0; k < K; ++k)
            acc = fmaf(a[k], W[k * Nc + n], acc);
        if (act == 1) acc = tanhf(acc);
        out[(row0 + r) * Nc + n] = acc;
    }
}

// ---------------------------------------------------------------------------
// One conv layer with TIME-SHARED weight buffers W0/W1 (4096 ush each):
//   stage W0=wq,W1=wk -> P1a (q,k) -> restage W0=wv,W1=we -> P1b (v,e)
// Weight LDS footprint halved 32KB->16KB so TWO 512-thr blocks fit the
// ~128KB usable pool (the r16 occupancy limiter).  All inner loops pure LDS.
// ---------------------------------------------------------------------------
template <int XD, int ED2>
__device__ __forceinline__ void conv_layer(
    const ushort_t* __restrict__ xs,   // [9][XD] bf16 LDS
    const ushort_t* __restrict__ es,   // [81][ED2] bf16 LDS
    const float* __restrict__ wq_g, const float* __restrict__ wk_g,
    const float* __restrict__ wv_g, const float* __restrict__ we_g,
    const float* __restrict__ weo_g,   // [2*XD+ED2][32] f32 global
    ushort_t* W0, ushort_t* W1,        // 2 x 4096 ush staging buffers
    ushort_t* weoL,                    // aliases W0 (wv dead after P1b)
    ushort_t* qT, ushort_t* kT, ushort_t* vT, ushort_t* eT,
    float* en, float* xn, float* la, int tid)
{
    // stage wq, wk
    for (int idx = tid; idx < XD * 128; idx += TPB) {
        W0[idx] = f2b(wq_g[idx]);
        W1[idx] = f2b(wk_g[idx]);
    }
    __syncthreads();

    // P1a: q,k projections (2*9*128)
    for (int idx = tid; idx < 2304; idx += TPB) {
        int which = idx / 1152, rem = idx - which * 1152;
        int node = rem >> 7, hd = rem & 127;
        int h = hd >> 5, d = hd & 31;
        const ushort_t* w = which ? W1 : W0;
        float acc = 0.f;
        #pragma unroll
        for (int m = 0; m < XD; ++m)
            acc = fmaf(b2f(xs[node * XD + m]), b2f(w[m * 128 + hd]), acc);
        ushort_t* dst = which ? kT : qT;
        dst[d * 38 + node * 4 + h] = f2b(acc);
    }
    __syncthreads();

    // restage wv, we (wq,wk dead)
    for (int idx = tid; idx < XD * 128; idx += TPB) W0[idx] = f2b(wv_g[idx]);
    for (int idx = tid; idx < ED2 * 128; idx += TPB) W1[idx] = f2b(we_g[idx]);
    __syncthreads();

    // P1b: v projection (1152) + e projection (81*128)
    for (int idx = tid; idx < 11520; idx += TPB) {
        if (idx < 1152) {
            int node = idx >> 7, hd = idx & 127;
            int h = hd >> 5, d = hd & 31;
            float acc = 0.f;
            #pragma unroll
            for (int m = 0; m < XD; ++m)
                acc = fmaf(b2f(xs[node * XD + m]), b2f(W0[m * 128 + hd]), acc);
            vT[d * 38 + node * 4 + h] = f2b(acc);
        } else {
            int r = idx - 1152;
            int le = r >> 7, hd = r & 127;
            int h = hd >> 5, d = hd & 31;
            float acc = 0.f;
            #pragma unroll
            for (int m = 0; m < ED2; ++m)
                acc = fmaf(b2f(es[le * ED2 + m]), b2f(W1[m * 128 + hd]), acc);
            eT[d * 324 + le * 4 + h] = f2b(acc);
        }
    }
    __syncthreads();

    // P2a: logits[le,h] -> la (aliases W1[0:648]; we dead after P1b)
    for (int idx = tid; idx < 324; idx += TPB) {
        int le = idx >> 2, h = idx & 3;
        int i = le / 9, j = le - i * 9;
        float acc = 0.f;
        #pragma unroll
        for (int d = 0; d < 32; ++d)
            acc = fmaf(b2f(qT[d * 38 + j * 4 + h]),
                       b2f(kT[d * 38 + i * 4 + h]) + b2f(eT[d * 324 + le * 4 + h]), acc);
        la[idx] = acc * 0.17677669529663687f;
    }
    __syncthreads();

    // P2b: segment softmax over src i, per (dst j, head h), in place
    for (int s = tid; s < 36; s += TPB) {
        int j = s >> 2, h = s & 3;
        float m = -1e30f;
        #pragma unroll
        for (int i = 0; i < 9; ++i) m = fmaxf(m, la[(i * 9 + j) * 4 + h]);
        float ex[9], sum = 0.f;
        #pragma unroll
        for (int i = 0; i < 9; ++i) { ex[i] = __expf(la[(i * 9 + j) * 4 + h] - m); sum += ex[i]; }
        float inv = 1.f / (sum + 1e-16f);
        #pragma unroll
        for (int i = 0; i < 9; ++i) la[(i * 9 + j) * 4 + h] = ex[i] * inv;
    }
    __syncthreads();

    // P3: aggregation -> xn (aliases qT[0:576]; qT dead after P2a)
    for (int idx = tid; idx < 288; idx += TPB) {
        int j = idx >> 5, d = idx & 31;
        float acc = 0.f;
        #pragma unroll
        for (int h = 0; h < 4; ++h)
            #pragma unroll
            for (int i = 0; i < 9; ++i) {
                int le = i * 9 + j;
                acc = fmaf(la[le * 4 + h],
                           b2f(vT[d * 38 + i * 4 + h]) + b2f(eT[d * 324 + le * 4 + h]), acc);
            }
        xn[idx] = acc * 0.25f;
    }
    __syncthreads();   // vT/eT/la reads done

    // stage weo into W0 (wv dead after P1b)
    for (int idx = tid; idx < (2 * XD + ED2) * 32; idx += TPB)
        weoL[idx] = f2b(weo_g[idx]);
    __syncthreads();

    // P4: edge out = concat(x[src], x[dst], e) @ weo -> en (aliases eT[0:5184])
    for (int idx = tid; idx < 2592; idx += TPB) {
        int le = idx >> 5, c = idx & 31;
        int i = le / 9, j = le - i * 9;
        float acc = 0.f;
        #pragma unroll
        for (int m = 0; m < XD;  ++m) acc = fmaf(b2f(xs[i * XD + m]),   b2f(weoL[m * 32 + c]), acc);
        #pragma unroll
        for (int m = 0; m < XD;  ++m) acc = fmaf(b2f(xs[j * XD + m]),   b2f(weoL[(XD + m) * 32 + c]), acc);
        #pragma unroll
        for (int m = 0; m < ED2; ++m) acc = fmaf(b2f(es[le * ED2 + m]), b2f(weoL[(2 * XD + m) * 32 + c]), acc);
        en[idx] = acc;
    }
    __syncthreads();   // xs/es reads done before caller overwrites xc/ec
}

// ---------------------------------------------------------------------------
// Fused GNN: 3 conv layers + finals.  512-thr block per graph.
// LDS = 25088 ush = 50176 B -> 2 blocks/CU fits the ~128KB usable pool
// (r16 falsified the 160KB assumption: 2x66560 did NOT co-reside).
// __launch_bounds__(512,2) -> VGPR cap 128 (r16: no spills at 128).
// Aliases (lifetime-audited, each pair barrier-separated):
//   weoL->W0, la->W1[0:648], xn->qT[0:576], en->eT[0:5184],
//   e0s->ec[0:405], x0s->xc[0:117].
// ---------------------------------------------------------------------------
__global__ __launch_bounds__(TPB, 2) void fused_gnn_kernel(
    const float* __restrict__ nl,    // [B, 117]
    const float* __restrict__ el,    // [B, 405]
    const float* __restrict__ c0_wq, const float* __restrict__ c0_wk,
    const float* __restrict__ c0_wv, const float* __restrict__ c0_we,
    const float* __restrict__ c0_weo,
    const float* __restrict__ c1_wq, const float* __restrict__ c1_wk,
    const float* __restrict__ c1_wv, const float* __restrict__ c1_we,
    const float* __restrict__ c1_weo,
    const float* __restrict__ ln0_g, const float* __restrict__ ln0_b,
    const float* __restrict__ ln1_g, const float* __restrict__ ln1_b,
    const float* __restrict__ w_feat, const float* __restrict__ w_eout,
    float* __restrict__ out)
{
    __shared__ ushort_t smu[25088];            // 50176 B
    ushort_t* W0   = smu;                      // [32][128] staging A
    ushort_t* W1   = smu + 4096;               // [32][128] staging B
    ushort_t* weoL = smu;                      // [96][32], aliases W0
    float*    la   = (float*)(smu + 4096);     // [81][4] f32, aliases W1[0:648]
    ushort_t* qT   = smu + 8192;               // [32][38]
    float*    xn   = (float*)(smu + 8192);     // [9][32] f32, aliases qT[0:576]
    ushort_t* kT   = smu + 9408;               // [32][38]
    ushort_t* vT   = smu + 10624;              // [32][38]
    ushort_t* eT   = smu + 11840;              // [32][324]
    float*    en   = (float*)(smu + 11840);    // [81][32] f32, aliases eT[0:5184]
    ushort_t* ec   = smu + 22208;              // [81][32] bf16
    ushort_t* e0s  = smu + 22208;              // [81][5] bf16, aliases ec
    ushort_t* xc   = smu + 24800;              // [9][32] bf16
    ushort_t* x0s  = smu + 24800;              // [9][13] bf16, aliases xc

    const int b   = blockIdx.x;
    const int tid = threadIdx.x;

    // stage layer-0 inputs (bf16)
    for (int idx = tid; idx < 117; idx += TPB) x0s[idx] = f2b(nl[b * 117 + idx]);
    for (int idx = tid; idx < 405; idx += TPB) {
        int le = idx / 5, c = idx - le * 5;
        int i = le / 9, j = le - i * 9;
        e0s[idx] = f2b(0.5f * (el[b * 405 + c * 81 + i * 9 + j] +
                               el[b * 405 + c * 81 + j * 9 + i]));
    }
    __syncthreads();

    for (int layer = 0; layer < 3; ++layer) {
        if (layer == 0)
            conv_layer<13, 5>(x0s, e0s, c0_wq, c0_wk, c0_wv, c0_we, c0_weo,
                              W0, W1, weoL, qT, kT, vT, eT, en, xn, la, tid);
        else
            conv_layer<32, 32>(xc, ec, c1_wq, c1_wk, c1_wv, c1_we, c1_weo,
                               W0, W1, weoL, qT, kT, vT, eT, en, xn, la, tid);

        // P5 (layers 0,1 only): x = leaky(LN(xn)), e = leaky(en)
        if (layer < 2) {
            const float* g  = (layer == 0) ? ln0_g : ln1_g;
            const float* be = (layer == 0) ? ln0_b : ln1_b;
            for (int idx = tid; idx < 288; idx += TPB) {
                int j = idx >> 5, c = idx & 31;
                float mu = 0.f;
                #pragma unroll
                for (int t = 0; t < 32; ++t) mu += xn[j * 32 + t];
                mu *= (1.f / 32.f);
                float var = 0.f;
                #pragma unroll
                for (int t = 0; t < 32; ++t) { float d = xn[j * 32 + t] - mu; var = fmaf(d, d, var); }
                var *= (1.f / 32.f);
                float val = (xn[idx] - mu) / sqrtf(var + 1e-5f);
                val = val * g[c] + be[c];
                xc[idx] = f2b((val > 0.f) ? val : 0.01f * val);
            }
            for (int idx = tid; idx < 2592; idx += TPB) {
                float v = en[idx];
                ec[idx] = f2b((v > 0.f) ? v : 0.01f * v);
            }
            __syncthreads();
        }
    }

    // Finals.  After layer 2 (no post): xn [9,32] f32, en [81,32] f32.
    float* out_x  = out;                       // [36864,10]
    float* out_e  = out + 368640;              // [294912,5]
    float* out_ei = out + 1843200;             // [2,294912]
    float* out_b  = out + 2433024;             // [36864]

    for (int idx = tid; idx < 90; idx += TPB) {         // x @ w_feat
        int j = idx / 10, c = idx - j * 10;
        float acc = 0.f;
        #pragma unroll
        for (int kk = 0; kk < 32; ++kk) acc = fmaf(xn[j * 32 + kk], w_feat[kk * 10 + c], acc);
        out_x[(b * 9 + j) * 10 + c] = acc;
    }
    for (int idx = tid; idx < 360; idx += TPB) {        // masked eattr @ w_eout
        int r = idx / 5, c = idx - r * 5;
        int i = r >> 3, jj = r & 7;
        int j = jj + (jj >= i ? 1 : 0);
        const float* row = &en[(i * 9 + j) * 32];
        float acc = 0.f;
        #pragma unroll
        for (int kk = 0; kk < 32; ++kk) acc = fmaf(row[kk], w_eout[kk * 5 + c], acc);
        out_e[(b * 72 + r) * 5 + c] = acc;
    }
    for (int idx = tid; idx < 72; idx += TPB) {         // edge_index
        int i = idx >> 3, jj = idx & 7;
        int j = jj + (jj >= i ? 1 : 0);
        out_ei[b * 72 + idx]          = (float)(b * 9 + i);
        out_ei[294912 + b * 72 + idx] = (float)(b * 9 + j);
    }
    for (int idx = tid; idx < 9; idx += TPB)            // batch
        out_b[b * 9 + idx] = (float)b;
}

// ---------------------------------------------------------------------------
extern "C" void kernel_launch(void* const* d_in, const int* in_sizes, int n_in,
                              void* d_out, int out_size, void* d_ws, size_t ws_size,
                              hipStream_t stream)
{
    const float* latent  = (const float*)d_in[0];
    const float* w_mlp0  = (const float*)d_in[1];
    const float* b_mlp0  = (const float*)d_in[2];
    const float* w_mlp1  = (const float*)d_in[3];
    const float* b_mlp1  = (const float*)d_in[4];
    const float* w_mlp2  = (const float*)d_in[5];
    const float* b_mlp2  = (const float*)d_in[6];
    const float* w_edges = (const float*)d_in[7];
    const float* b_edges = (const float*)d_in[8];
    const float* w_nodes = (const float*)d_in[9];
    const float* b_nodes = (const float*)d_in[10];
    const float* c0_wq   = (const float*)d_in[11];
    const float* c0_wk   = (const float*)d_in[12];
    const float* c0_wv   = (const float*)d_in[13];
    const float* c0_we   = (const float*)d_in[14];
    const float* c0_weo  = (const float*)d_in[15];
    const float* c1_wq   = (const float*)d_in[16];
    const float* c1_wk   = (const float*)d_in[17];
    const float* c1_wv   = (const float*)d_in[18];
    const float* c1_we   = (const float*)d_in[19];
    const float* c1_weo  = (const float*)d_in[20];
    const float* ln0_g   = (const float*)d_in[21];
    const float* ln0_b   = (const float*)d_in[22];
    const float* ln1_g   = (const float*)d_in[23];
    const float* ln1_b   = (const float*)d_in[24];
    const float* w_feat  = (const float*)d_in[25];
    const float* w_eout  = (const float*)d_in[26];

    // Workspace layout with lifetime overlap (peak 18.3 MB)
    float* ws = (float*)d_ws;
    float* h0 = ws;
    float* el = ws;
    float* h1 = ws + 1658880;
    float* nl = ws + 1658880;
    float* h2 = ws + 2707456;

    float* out = (float*)d_out;

    gemm_act_kernel<<<512, 256, 0, stream>>>(latent, w_mlp0, b_mlp0, h0, 128, 128, 1);
    gemm_act_kernel<<<512, 256, 0, stream>>>(h0, w_mlp1, b_mlp1, h1, 128, 256, 1);
    gemm_act_kernel<<<512, 256, 0, stream>>>(h1, w_mlp2, b_mlp2, h2, 256, 512, 1);
    gemm_act_kernel<<<512, 256, 0, stream>>>(h2, w_edges, b_edges, el, 512, 405, 0);
    gemm_act_kernel<<<512, 256, 0, stream>>>(h2, w_nodes, b_nodes, nl, 512, 117, 0);

    fused_gnn_kernel<<<B_, TPB, 0, stream>>>(nl, el,
        c0_wq, c0_wk, c0_wv, c0_we, c0_weo,
        c1_wq, c1_wk, c1_wv, c1_we, c1_weo,
        ln0_g, ln0_b, ln1_g, ln1_b, w_feat, w_eout, out);
}

// Round 18
// 1062.360 us; speedup vs baseline: 1.2963x; 1.2963x over previous
//
#include <hip/hip_runtime.h>
#include <hip/hip_bf16.h>
#include <math.h>

#define B_    4096
#define V_    9
#define N_    (B_*V_)          // 36864 nodes
#define EK_   (B_*V_*(V_-1))   // 294912 kept edges
#define TPB   512

typedef unsigned short ushort_t;

__device__ __forceinline__ float b2f(ushort_t u) {
    union { unsigned int i; float f; } x; x.i = ((unsigned int)u) << 16; return x.f;
}
__device__ __forceinline__ ushort_t f2b(float f) {
    union { float f; unsigned int i; } x; x.f = f;
    unsigned int r = x.i + 0x7FFFu + ((x.i >> 16) & 1u);
    return (ushort_t)(r >> 16);
}

// ---------------------------------------------------------------------------
// Batched GEMM for the MLP head (unchanged this round)
// ---------------------------------------------------------------------------
__global__ __launch_bounds__(256) void gemm_act_kernel(
    const float* __restrict__ A, const float* __restrict__ W,
    const float* __restrict__ bias, float* __restrict__ out,
    int K, int Nc, int act)
{
    __shared__ float As[8 * 512];
    const int row0 = blockIdx.x * 8;
    const int tid  = threadIdx.x;

    for (int idx = tid; idx < 8 * K; idx += 256)
        As[idx] = A[row0 * K + idx];
    __syncthreads();

    const int total = 8 * Nc;
    for (int idx = tid; idx < total; idx += 256) {
        int r = idx / Nc;
        int n = idx - r * Nc;
        float acc = bias[n];
        const float* a = &As[r * K];
        for (int k = 0; k < K; ++k)
            acc = fmaf(a[k], W[k * Nc + n], acc);
        if (act == 1) acc = tanhf(acc);
        out[(row0 + r) * Nc + n] = acc;
    }
}

// ---------------------------------------------------------------------------
// One conv layer, register-tiled.  Weights staged f32 in LDS (no cvt, b128
// broadcast reads); activations xs/es f32 stride-33 (bank-spread).  Each
// thread owns 8 output columns x 1-3 rows; per k-step 2 broadcast b128 +
// 1-3 b32 feed 8-24 FMAs -> VALU-bound, not LDS-bound.
// Occupancy is pinned at 1 block/CU by the VGPR AGPR-shadow (r17 analysis),
// so LDS is spent freely: NO buffer aliasing.
// ---------------------------------------------------------------------------
template <int XD, int ED2>
__device__ __forceinline__ void conv_layer(
    float* __restrict__ xs,            // [9][33] f32 (state in/out)
    float* __restrict__ es,            // [81][33] f32 (state in/out)
    const float* __restrict__ wq_g, const float* __restrict__ wk_g,
    const float* __restrict__ wv_g, const float* __restrict__ we_g,
    const float* __restrict__ weo_g,
    float* W0, float* W1, float* weoL, // [32][128],[32][128],[96][32] f32
    ushort_t* qT, ushort_t* kT, ushort_t* vT, ushort_t* eT,
    float* en, float* xn, float* la, int tid)
{
    // stage wq, wk (plain f32 copies)
    for (int idx = tid; idx < XD * 128; idx += TPB) {
        W0[idx] = wq_g[idx];
        W1[idx] = wk_g[idx];
    }
    __syncthreads();

    // P1a: q,k projections.  288 tasks: t = mat*144 + hdgrp*9 + node
    for (int t = tid; t < 288; t += TPB) {
        int mat = t / 144, r = t - mat * 144;
        int hdgrp = r / 9, node = r - hdgrp * 9;
        int hd0 = hdgrp * 8;
        const float* w = mat ? W1 : W0;
        float acc[8];
        #pragma unroll
        for (int u = 0; u < 8; ++u) acc[u] = 0.f;
        #pragma unroll 2
        for (int m = 0; m < XD; ++m) {
            float xv = xs[node * 33 + m];
            const float* wrow = &w[m * 128 + hd0];
            #pragma unroll
            for (int u = 0; u < 8; ++u) acc[u] = fmaf(xv, wrow[u], acc[u]);
        }
        ushort_t* dst = mat ? kT : qT;
        #pragma unroll
        for (int u = 0; u < 8; ++u) {
            int hd = hd0 + u, h = hd >> 5, d = hd & 31;
            dst[d * 38 + node * 4 + h] = f2b(acc[u]);
        }
    }
    __syncthreads();

    // stage wv, we, weo (weoL is a SEPARATE buffer -> no lifetime hazard)
    for (int idx = tid; idx < XD * 128; idx += TPB) W0[idx] = wv_g[idx];
    for (int idx = tid; idx < ED2 * 128; idx += TPB) W1[idx] = we_g[idx];
    for (int idx = tid; idx < (2 * XD + ED2) * 32; idx += TPB) weoL[idx] = weo_g[idx];
    __syncthreads();

    // P1b: e-proj (432 tasks: t = hdgrp*27 + legrp, 3 le each) + v-proj (144)
    for (int t = tid; t < 576; t += TPB) {
        if (t < 432) {
            int hdgrp = t / 27, legrp = t - hdgrp * 27;
            int hd0 = hdgrp * 8, le0 = legrp * 3;
            float acc[3][8];
            #pragma unroll
            for (int l = 0; l < 3; ++l)
                #pragma unroll
                for (int u = 0; u < 8; ++u) acc[l][u] = 0.f;
            #pragma unroll 2
            for (int m = 0; m < ED2; ++m) {
                const float* wrow = &W1[m * 128 + hd0];
                #pragma unroll
                for (int l = 0; l < 3; ++l) {
                    float ev = es[(le0 + l) * 33 + m];
                    #pragma unroll
                    for (int u = 0; u < 8; ++u)
                        acc[l][u] = fmaf(ev, wrow[u], acc[l][u]);
                }
            }
            #pragma unroll
            for (int l = 0; l < 3; ++l) {
                int le = le0 + l;
                #pragma unroll
                for (int u = 0; u < 8; ++u) {
                    int hd = hd0 + u, h = hd >> 5, d = hd & 31;
                    eT[d * 324 + le * 4 + h] = f2b(acc[l][u]);
                }
            }
        } else {
            int r = t - 432;
            int hdgrp = r / 9, node = r - hdgrp * 9;
            int hd0 = hdgrp * 8;
            float acc[8];
            #pragma unroll
            for (int u = 0; u < 8; ++u) acc[u] = 0.f;
            #pragma unroll 2
            for (int m = 0; m < XD; ++m) {
                float xv = xs[node * 33 + m];
                const float* wrow = &W0[m * 128 + hd0];
                #pragma unroll
                for (int u = 0; u < 8; ++u) acc[u] = fmaf(xv, wrow[u], acc[u]);
            }
            #pragma unroll
            for (int u = 0; u < 8; ++u) {
                int hd = hd0 + u, h = hd >> 5, d = hd & 31;
                vT[d * 38 + node * 4 + h] = f2b(acc[u]);
            }
        }
    }
    __syncthreads();

    // P2a: logits[le,h] = (q[dst=j] . (k[src=i]+e)) / sqrt(32)   (r17 verbatim)
    for (int idx = tid; idx < 324; idx += TPB) {
        int le = idx >> 2, h = idx & 3;
        int i = le / 9, j = le - i * 9;
        float acc = 0.f;
        #pragma unroll
        for (int d = 0; d < 32; ++d)
            acc = fmaf(b2f(qT[d * 38 + j * 4 + h]),
                       b2f(kT[d * 38 + i * 4 + h]) + b2f(eT[d * 324 + le * 4 + h]), acc);
        la[idx] = acc * 0.17677669529663687f;
    }
    __syncthreads();

    // P2b: segment softmax over src i per (dst j, head h)        (r17 verbatim)
    for (int s = tid; s < 36; s += TPB) {
        int j = s >> 2, h = s & 3;
        float m = -1e30f;
        #pragma unroll
        for (int i = 0; i < 9; ++i) m = fmaxf(m, la[(i * 9 + j) * 4 + h]);
        float ex[9], sum = 0.f;
        #pragma unroll
        for (int i = 0; i < 9; ++i) { ex[i] = __expf(la[(i * 9 + j) * 4 + h] - m); sum += ex[i]; }
        float inv = 1.f / (sum + 1e-16f);
        #pragma unroll
        for (int i = 0; i < 9; ++i) la[(i * 9 + j) * 4 + h] = ex[i] * inv;
    }
    __syncthreads();

    // P3: aggregation -> xn[j,d]                                  (r17 verbatim)
    for (int idx = tid; idx < 288; idx += TPB) {
        int j = idx >> 5, d = idx & 31;
        float acc = 0.f;
        #pragma unroll
        for (int h = 0; h < 4; ++h)
            #pragma unroll
            for (int i = 0; i < 9; ++i) {
                int le = i * 9 + j;
                acc = fmaf(la[le * 4 + h],
                           b2f(vT[d * 38 + i * 4 + h]) + b2f(eT[d * 324 + le * 4 + h]), acc);
            }
        xn[idx] = acc * 0.25f;
    }
    __syncthreads();

    // P4: edge out, register-tiled.  324 tasks: t = cgrp*81 + le (8 cols each)
    for (int t = tid; t < 324; t += TPB) {
        int cgrp = t / 81, le = t - cgrp * 81;
        int c0 = cgrp * 8;
        int i = le / 9, j = le - i * 9;
        float acc[8];
        #pragma unroll
        for (int u = 0; u < 8; ++u) acc[u] = 0.f;
        #pragma unroll 2
        for (int k = 0; k < XD; ++k) {
            float a = xs[i * 33 + k];
            const float* wrow = &weoL[k * 32 + c0];
            #pragma unroll
            for (int u = 0; u < 8; ++u) acc[u] = fmaf(a, wrow[u], acc[u]);
        }
        #pragma unroll 2
        for (int k = 0; k < XD; ++k) {
            float a = xs[j * 33 + k];
            const float* wrow = &weoL[(XD + k) * 32 + c0];
            #pragma unroll
            for (int u = 0; u < 8; ++u) acc[u] = fmaf(a, wrow[u], acc[u]);
        }
        #pragma unroll 2
        for (int k = 0; k < ED2; ++k) {
            float a = es[le * 33 + k];
            const float* wrow = &weoL[(2 * XD + k) * 32 + c0];
            #pragma unroll
            for (int u = 0; u < 8; ++u) acc[u] = fmaf(a, wrow[u], acc[u]);
        }
        #pragma unroll
        for (int u = 0; u < 8; ++u) en[le * 32 + c0 + u] = acc[u];
    }
    __syncthreads();
}

// ---------------------------------------------------------------------------
// Fused GNN: 3 conv layers + finals.  512-thr block per graph, 1 block/CU
// (accepted: AGPR-shadow makes 2x512-thr need VGPR<=64 which spills).
// LDS ~97.8KB, NO aliases.  __launch_bounds__(512,2) -> VGPR cap 128
// (proven no-spill regime, r16/r17).
// ---------------------------------------------------------------------------
__global__ __launch_bounds__(TPB, 2) void fused_gnn_kernel(
    const float* __restrict__ nl,    // [B, 117]
    const float* __restrict__ el,    // [B, 405]
    const float* __restrict__ c0_wq, const float* __restrict__ c0_wk,
    const float* __restrict__ c0_wv, const float* __restrict__ c0_we,
    const float* __restrict__ c0_weo,
    const float* __restrict__ c1_wq, const float* __restrict__ c1_wk,
    const float* __restrict__ c1_wv, const float* __restrict__ c1_we,
    const float* __restrict__ c1_weo,
    const float* __restrict__ ln0_g, const float* __restrict__ ln0_b,
    const float* __restrict__ ln1_g, const float* __restrict__ ln1_b,
    const float* __restrict__ w_feat, const float* __restrict__ w_eout,
    float* __restrict__ out)
{
    __shared__ float    W0[32 * 128];      // 16384 B
    __shared__ float    W1[32 * 128];      // 16384 B
    __shared__ float    weoL[96 * 32];     // 12288 B
    __shared__ float    xs[9 * 33];        //  1188 B
    __shared__ float    es[81 * 33];       // 10692 B
    __shared__ float    la[324];           //  1296 B
    __shared__ float    xn[288];           //  1152 B
    __shared__ float    en[81 * 32];       // 10368 B
    __shared__ ushort_t qT[32 * 38];       //  2432 B
    __shared__ ushort_t kT[32 * 38];
    __shared__ ushort_t vT[32 * 38];
    __shared__ ushort_t eT[32 * 324];      // 20736 B

    const int b   = blockIdx.x;
    const int tid = threadIdx.x;

    // stage layer-0 inputs (f32, stride-33 padded)
    for (int idx = tid; idx < 117; idx += TPB) {
        int node = idx / 13, m = idx - node * 13;
        xs[node * 33 + m] = nl[b * 117 + idx];
    }
    for (int idx = tid; idx < 405; idx += TPB) {
        int le = idx / 5, c = idx - le * 5;
        int i = le / 9, j = le - i * 9;
        es[le * 33 + c] = 0.5f * (el[b * 405 + c * 81 + i * 9 + j] +
                                  el[b * 405 + c * 81 + j * 9 + i]);
    }
    __syncthreads();

    for (int layer = 0; layer < 3; ++layer) {
        if (layer == 0)
            conv_layer<13, 5>(xs, es, c0_wq, c0_wk, c0_wv, c0_we, c0_weo,
                              W0, W1, weoL, qT, kT, vT, eT, en, xn, la, tid);
        else
            conv_layer<32, 32>(xs, es, c1_wq, c1_wk, c1_wv, c1_we, c1_weo,
                               W0, W1, weoL, qT, kT, vT, eT, en, xn, la, tid);

        // P5 (layers 0,1 only): x = leaky(LN(xn)) -> xs; e = leaky(en) -> es
        if (layer < 2) {
            const float* g  = (layer == 0) ? ln0_g : ln1_g;
            const float* be = (layer == 0) ? ln0_b : ln1_b;
            for (int idx = tid; idx < 288; idx += TPB) {
                int j = idx >> 5, c = idx & 31;
                float mu = 0.f;
                #pragma unroll
                for (int t = 0; t < 32; ++t) mu += xn[j * 32 + t];
                mu *= (1.f / 32.f);
                float var = 0.f;
                #pragma unroll
                for (int t = 0; t < 32; ++t) { float d = xn[j * 32 + t] - mu; var = fmaf(d, d, var); }
                var *= (1.f / 32.f);
                float val = (xn[idx] - mu) / sqrtf(var + 1e-5f);
                val = val * g[c] + be[c];
                xs[j * 33 + c] = (val > 0.f) ? val : 0.01f * val;
            }
            for (int idx = tid; idx < 2592; idx += TPB) {
                int le = idx >> 5, c = idx & 31;
                float v = en[idx];
                es[le * 33 + c] = (v > 0.f) ? v : 0.01f * v;
            }
            __syncthreads();
        }
    }

    // Finals.  After layer 2 (no post): xn [9,32] f32, en [81,32] f32.
    float* out_x  = out;                       // [36864,10]
    float* out_e  = out + 368640;              // [294912,5]
    float* out_ei = out + 1843200;             // [2,294912]
    float* out_b  = out + 2433024;             // [36864]

    for (int idx = tid; idx < 90; idx += TPB) {         // x @ w_feat
        int j = idx / 10, c = idx - j * 10;
        float acc = 0.f;
        #pragma unroll
        for (int kk = 0; kk < 32; ++kk) acc = fmaf(xn[j * 32 + kk], w_feat[kk * 10 + c], acc);
        out_x[(b * 9 + j) * 10 + c] = acc;
    }
    for (int idx = tid; idx < 360; idx += TPB) {        // masked eattr @ w_eout
        int r = idx / 5, c = idx - r * 5;
        int i = r >> 3, jj = r & 7;
        int j = jj + (jj >= i ? 1 : 0);
        const float* row = &en[(i * 9 + j) * 32];
        float acc = 0.f;
        #pragma unroll
        for (int kk = 0; kk < 32; ++kk) acc = fmaf(row[kk], w_eout[kk * 5 + c], acc);
        out_e[(b * 72 + r) * 5 + c] = acc;
    }
    for (int idx = tid; idx < 72; idx += TPB) {         // edge_index
        int i = idx >> 3, jj = idx & 7;
        int j = jj + (jj >= i ? 1 : 0);
        out_ei[b * 72 + idx]          = (float)(b * 9 + i);
        out_ei[294912 + b * 72 + idx] = (float)(b * 9 + j);
    }
    for (int idx = tid; idx < 9; idx += TPB)            // batch
        out_b[b * 9 + idx] = (float)b;
}

// ---------------------------------------------------------------------------
extern "C" void kernel_launch(void* const* d_in, const int* in_sizes, int n_in,
                              void* d_out, int out_size, void* d_ws, size_t ws_size,
                              hipStream_t stream)
{
    const float* latent  = (const float*)d_in[0];
    const float* w_mlp0  = (const float*)d_in[1];
    const float* b_mlp0  = (const float*)d_in[2];
    const float* w_mlp1  = (const float*)d_in[3];
    const float* b_mlp1  = (const float*)d_in[4];
    const float* w_mlp2  = (const float*)d_in[5];
    const float* b_mlp2  = (const float*)d_in[6];
    const float* w_edges = (const float*)d_in[7];
    const float* b_edges = (const float*)d_in[8];
    const float* w_nodes = (const float*)d_in[9];
    const float* b_nodes = (const float*)d_in[10];
    const float* c0_wq   = (const float*)d_in[11];
    const float* c0_wk   = (const float*)d_in[12];
    const float* c0_wv   = (const float*)d_in[13];
    const float* c0_we   = (const float*)d_in[14];
    const float* c0_weo  = (const float*)d_in[15];
    const float* c1_wq   = (const float*)d_in[16];
    const float* c1_wk   = (const float*)d_in[17];
    const float* c1_wv   = (const float*)d_in[18];
    const float* c1_we   = (const float*)d_in[19];
    const float* c1_weo  = (const float*)d_in[20];
    const float* ln0_g   = (const float*)d_in[21];
    const float* ln0_b   = (const float*)d_in[22];
    const float* ln1_g   = (const float*)d_in[23];
    const float* ln1_b   = (const float*)d_in[24];
    const float* w_feat  = (const float*)d_in[25];
    const float* w_eout  = (const float*)d_in[26];

    // Workspace layout with lifetime overlap (peak 18.3 MB)
    float* ws = (float*)d_ws;
    float* h0 = ws;
    float* el = ws;
    float* h1 = ws + 1658880;
    float* nl = ws + 1658880;
    float* h2 = ws + 2707456;

    float* out = (float*)d_out;

    gemm_act_kernel<<<512, 256, 0, stream>>>(latent, w_mlp0, b_mlp0, h0, 128, 128, 1);
    gemm_act_kernel<<<512, 256, 0, stream>>>(h0, w_mlp1, b_mlp1, h1, 128, 256, 1);
    gemm_act_kernel<<<512, 256, 0, stream>>>(h1, w_mlp2, b_mlp2, h2, 256, 512, 1);
    gemm_act_kernel<<<512, 256, 0, stream>>>(h2, w_edges, b_edges, el, 512, 405, 0);
    gemm_act_kernel<<<512, 256, 0, stream>>>(h2, w_nodes, b_nodes, nl, 512, 117, 0);

    fused_gnn_kernel<<<B_, TPB, 0, stream>>>(nl, el,
        c0_wq, c0_wk, c0_wv, c0_we, c0_weo,
        c1_wq, c1_wk, c1_wv, c1_we, c1_weo,
        ln0_g, ln0_b, ln1_g, ln1_b, w_feat, w_eout, out);
}

// Round 21
// 905.531 us; speedup vs baseline: 1.5208x; 1.1732x over previous
//
#include <hip/hip_runtime.h>
#include <hip/hip_bf16.h>
#include <math.h>

#define B_    4096
#define V_    9
#define N_    (B_*V_)          // 36864 nodes
#define EK_   (B_*V_*(V_-1))   // 294912 kept edges
#define TPB   512

typedef unsigned short ushort_t;
typedef __attribute__((ext_vector_type(8))) short bf16x8;   // 8 bf16 (4 VGPRs)
typedef __attribute__((ext_vector_type(4))) float f32x4;    // 4 f32 acc

__device__ __forceinline__ float b2f(ushort_t u) {
    union { unsigned int i; float f; } x; x.i = ((unsigned int)u) << 16; return x.f;
}
__device__ __forceinline__ ushort_t f2b(float f) {
    union { float f; unsigned int i; } x; x.f = f;
    unsigned int r = x.i + 0x7FFFu + ((x.i >> 16) & 1u);
    return (ushort_t)(r >> 16);
}

// ---------------------------------------------------------------------------
// Batched GEMM for the MLP head (unchanged)
// ---------------------------------------------------------------------------
__global__ __launch_bounds__(256) void gemm_act_kernel(
    const float* __restrict__ A, const float* __restrict__ W,
    const float* __restrict__ bias, float* __restrict__ out,
    int K, int Nc, int act)
{
    __shared__ float As[8 * 512];
    const int row0 = blockIdx.x * 8;
    const int tid  = threadIdx.x;

    for (int idx = tid; idx < 8 * K; idx += 256)
        As[idx] = A[row0 * K + idx];
    __syncthreads();

    const int total = 8 * Nc;
    for (int idx = tid; idx < total; idx += 256) {
        int r = idx / Nc;
        int n = idx - r * Nc;
        float acc = bias[n];
        const float* a = &As[r * K];
        for (int k = 0; k < K; ++k)
            acc = fmaf(a[k], W[k * Nc + n], acc);
        if (act == 1) acc = tanhf(acc);
        out[(row0 + r) * Nc + n] = acc;
    }
}

// ---------------------------------------------------------------------------
// MFMA conv layer.  Heavy matmuls (q/k/v/e proj, edge-MLP) on the matrix
// pipe via mfma_f32_16x16x32_bf16; fragment layouts:
//   A: lane l -> row (l&15), k = (l>>4)*8 + e   (row-major, 16B b128 read)
//   B: lane l -> col (l&15), k = (l>>4)*8 + e   (weights staged TRANSPOSED)
//   D: lane l -> col (l&15), row = (l>>4)*4 + r (m89-verified)
// Strides 40/104 ush are 16B-aligned and 2-way-conflict-only (20/52 % 32).
// ---------------------------------------------------------------------------
template <int XD, int ED2>
__device__ __forceinline__ void conv_layer(
    ushort_t* xsb, ushort_t* esb,          // [16][40], [96][40] bf16 state
    const float* __restrict__ wq_g, const float* __restrict__ wk_g,
    const float* __restrict__ wv_g, const float* __restrict__ we_g,
    const float* __restrict__ weo_g,
    ushort_t* wT0, ushort_t* wT1,          // [128][40] transposed weights
    ushort_t* weoT,                        // [32][104] transposed weo
    ushort_t* qb, ushort_t* kb, ushort_t* vb,  // [16][132] bf16
    ushort_t* ehb,                         // [96][132] bf16
    ushort_t* Ab,                          // [96][104] bf16 concat A
    float* en, float* xn, float* la, int tid)
{
    const int wv_  = tid >> 6;
    const int lane = tid & 63;
    const int l15  = lane & 15;
    const int kg   = lane >> 4;          // k0 = kg*8

    // S1: stage wq^T, wk^T (zero-pad rows m>=XD)
    for (int idx = tid; idx < 4096; idx += TPB) {
        int m = idx >> 7, n = idx & 127;
        wT0[n * 40 + m] = (m < XD) ? f2b(wq_g[m * 128 + n]) : (ushort_t)0;
        wT1[n * 40 + m] = (m < XD) ? f2b(wk_g[m * 128 + n]) : (ushort_t)0;
    }
    __syncthreads();

    // P1a: q,k = xs @ wq/wk   (16 wave-tasks)
    for (int task = wv_; task < 16; task += 8) {
        int mat = task >> 3, nt = task & 7;
        bf16x8 a = *(const bf16x8*)&xsb[l15 * 40 + kg * 8];
        const ushort_t* wt = mat ? wT1 : wT0;
        bf16x8 bf = *(const bf16x8*)&wt[(nt * 16 + l15) * 40 + kg * 8];
        f32x4 d = {0.f, 0.f, 0.f, 0.f};
        d = __builtin_amdgcn_mfma_f32_16x16x32_bf16(a, bf, d, 0, 0, 0);
        ushort_t* dst = mat ? kb : qb;
        #pragma unroll
        for (int r = 0; r < 4; ++r)
            dst[(kg * 4 + r) * 132 + nt * 16 + l15] = f2b(d[r]);
    }
    __syncthreads();

    // S2: stage wv^T, we^T, weo^T
    for (int idx = tid; idx < 4096; idx += TPB) {
        int m = idx >> 7, n = idx & 127;
        wT0[n * 40 + m] = (m < XD)  ? f2b(wv_g[m * 128 + n]) : (ushort_t)0;
        wT1[n * 40 + m] = (m < ED2) ? f2b(we_g[m * 128 + n]) : (ushort_t)0;
    }
    for (int idx = tid; idx < 3072; idx += TPB) {
        int r = idx >> 5, c = idx & 31;
        weoT[c * 104 + r] = (r < 2 * XD + ED2) ? f2b(weo_g[r * 32 + c]) : (ushort_t)0;
    }
    __syncthreads();

    // P1b: v = xs @ wv (8 tasks) + eh = es @ we (48 tasks)
    for (int task = wv_; task < 56; task += 8) {
        if (task < 8) {
            int nt = task;
            bf16x8 a = *(const bf16x8*)&xsb[l15 * 40 + kg * 8];
            bf16x8 bf = *(const bf16x8*)&wT0[(nt * 16 + l15) * 40 + kg * 8];
            f32x4 d = {0.f, 0.f, 0.f, 0.f};
            d = __builtin_amdgcn_mfma_f32_16x16x32_bf16(a, bf, d, 0, 0, 0);
            #pragma unroll
            for (int r = 0; r < 4; ++r)
                vb[(kg * 4 + r) * 132 + nt * 16 + l15] = f2b(d[r]);
        } else {
            int t2 = task - 8, mt = t2 >> 3, nt = t2 & 7;
            bf16x8 a = *(const bf16x8*)&esb[(mt * 16 + l15) * 40 + kg * 8];
            bf16x8 bf = *(const bf16x8*)&wT1[(nt * 16 + l15) * 40 + kg * 8];
            f32x4 d = {0.f, 0.f, 0.f, 0.f};
            d = __builtin_amdgcn_mfma_f32_16x16x32_bf16(a, bf, d, 0, 0, 0);
            #pragma unroll
            for (int r = 0; r < 4; ++r)
                ehb[(mt * 16 + kg * 4 + r) * 132 + nt * 16 + l15] = f2b(d[r]);
        }
    }
    __syncthreads();

    // P2a: logits[le,h] = (q[dst=j] . (k[src=i]+eh)) / sqrt(32)
    for (int idx = tid; idx < 324; idx += TPB) {
        int le = idx >> 2, h = idx & 3;
        int i = le / 9, j = le - i * 9;
        const ushort_t* qp = &qb[j * 132 + h * 32];
        const ushort_t* kp = &kb[i * 132 + h * 32];
        const ushort_t* ep = &ehb[le * 132 + h * 32];
        float acc = 0.f;
        #pragma unroll
        for (int d = 0; d < 32; ++d)
            acc = fmaf(b2f(qp[d]), b2f(kp[d]) + b2f(ep[d]), acc);
        la[idx] = acc * 0.17677669529663687f;
    }
    __syncthreads();

    // P2b: segment softmax over src i per (dst j, head h)
    for (int s = tid; s < 36; s += TPB) {
        int j = s >> 2, h = s & 3;
        float m = -1e30f;
        #pragma unroll
        for (int i = 0; i < 9; ++i) m = fmaxf(m, la[(i * 9 + j) * 4 + h]);
        float ex[9], sum = 0.f;
        #pragma unroll
        for (int i = 0; i < 9; ++i) { ex[i] = __expf(la[(i * 9 + j) * 4 + h] - m); sum += ex[i]; }
        float inv = 1.f / (sum + 1e-16f);
        #pragma unroll
        for (int i = 0; i < 9; ++i) la[(i * 9 + j) * 4 + h] = ex[i] * inv;
    }
    __syncthreads();

    // P3: aggregation -> xn[j,d];  merged: build concat-A for P4
    for (int idx = tid; idx < 288; idx += TPB) {
        int j = idx >> 5, d = idx & 31;
        float acc = 0.f;
        #pragma unroll
        for (int h = 0; h < 4; ++h)
            #pragma unroll
            for (int i = 0; i < 9; ++i) {
                int le = i * 9 + j;
                acc = fmaf(la[le * 4 + h],
                           b2f(vb[i * 132 + h * 32 + d]) + b2f(ehb[le * 132 + h * 32 + d]), acc);
            }
        xn[idx] = acc * 0.25f;
    }
    for (int idx = tid; idx < 96 * 96; idx += TPB) {
        int le = idx / 96, k = idx - le * 96;
        int i = le / 9, j = le - i * 9;     // le>=81: i<=10 -> zero rows of xsb
        ushort_t v = 0;
        if (XD == 13) {
            if (k < 13)      v = xsb[i * 40 + k];
            else if (k < 26) v = xsb[j * 40 + (k - 13)];
            else if (k < 31) v = esb[le * 40 + (k - 26)];
        } else {
            if (k < 32)      v = xsb[i * 40 + k];
            else if (k < 64) v = xsb[j * 40 + (k - 32)];
            else             v = esb[le * 40 + (k - 64)];
        }
        Ab[le * 104 + k] = v;
    }
    __syncthreads();

    // P4: en = concat(x_src,x_dst,e) @ weo   (12 wave-tasks x KS k-steps)
    const int KS = (XD == 13) ? 1 : 3;
    for (int task = wv_; task < 12; task += 8) {
        int mt = task >> 1, nt = task & 1;
        f32x4 d = {0.f, 0.f, 0.f, 0.f};
        #pragma unroll
        for (int ks = 0; ks < KS; ++ks) {
            bf16x8 a = *(const bf16x8*)&Ab[(mt * 16 + l15) * 104 + ks * 32 + kg * 8];
            bf16x8 bf = *(const bf16x8*)&weoT[(nt * 16 + l15) * 104 + ks * 32 + kg * 8];
            d = __builtin_amdgcn_mfma_f32_16x16x32_bf16(a, bf, d, 0, 0, 0);
        }
        #pragma unroll
        for (int r = 0; r < 4; ++r) {
            int row = mt * 16 + kg * 4 + r;
            if (row < 81) en[row * 32 + nt * 16 + l15] = d[r];
        }
    }
    __syncthreads();
}

// ---------------------------------------------------------------------------
// Fused GNN, MFMA edition.  512-thr block per graph (1 block/CU accepted).
// LDS ~107KB, no aliasing.  __launch_bounds__(512,2) -> VGPR cap 128.
// ---------------------------------------------------------------------------
__global__ __launch_bounds__(TPB, 2) void fused_gnn_kernel(
    const float* __restrict__ nl,    // [B, 117]
    const float* __restrict__ el,    // [B, 405]
    const float* __restrict__ c0_wq, const float* __restrict__ c0_wk,
    const float* __restrict__ c0_wv, const float* __restrict__ c0_we,
    const float* __restrict__ c0_weo,
    const float* __restrict__ c1_wq, const float* __restrict__ c1_wk,
    const float* __restrict__ c1_wv, const float* __restrict__ c1_we,
    const float* __restrict__ c1_weo,
    const float* __restrict__ ln0_g, const float* __restrict__ ln0_b,
    const float* __restrict__ ln1_g, const float* __restrict__ ln1_b,
    const float* __restrict__ w_feat, const float* __restrict__ w_eout,
    float* __restrict__ out)
{
    __shared__ __align__(16) ushort_t xsb[16 * 40];     // bf16 x-state (pad rows/cols 0)
    __shared__ __align__(16) ushort_t esb[96 * 40];     // bf16 e-state
    __shared__ __align__(16) ushort_t wT0[128 * 40];    // W^T staging
    __shared__ __align__(16) ushort_t wT1[128 * 40];
    __shared__ __align__(16) ushort_t weoT[32 * 104];
    __shared__ __align__(16) ushort_t qb[16 * 132];
    __shared__ __align__(16) ushort_t kb[16 * 132];
    __shared__ __align__(16) ushort_t vb[16 * 132];
    __shared__ __align__(16) ushort_t ehb[96 * 132];
    __shared__ __align__(16) ushort_t Ab[96 * 104];
    __shared__ float en[81 * 32];
    __shared__ float la[324];
    __shared__ float xn[288];

    const int b   = blockIdx.x;
    const int tid = threadIdx.x;

    // zero padded state buffers, then stage layer-0 inputs
    for (int idx = tid; idx < 16 * 40; idx += TPB) xsb[idx] = 0;
    for (int idx = tid; idx < 96 * 40; idx += TPB) esb[idx] = 0;
    __syncthreads();
    for (int idx = tid; idx < 117; idx += TPB) {
        int node = idx / 13, m = idx - node * 13;
        xsb[node * 40 + m] = f2b(nl[b * 117 + idx]);
    }
    for (int idx = tid; idx < 405; idx += TPB) {
        int le = idx / 5, c = idx - le * 5;
        int i = le / 9, j = le - i * 9;
        esb[le * 40 + c] = f2b(0.5f * (el[b * 405 + c * 81 + i * 9 + j] +
                                       el[b * 405 + c * 81 + j * 9 + i]));
    }
    __syncthreads();

    for (int layer = 0; layer < 3; ++layer) {
        if (layer == 0)
            conv_layer<13, 5>(xsb, esb, c0_wq, c0_wk, c0_wv, c0_we, c0_weo,
                              wT0, wT1, weoT, qb, kb, vb, ehb, Ab, en, xn, la, tid);
        else
            conv_layer<32, 32>(xsb, esb, c1_wq, c1_wk, c1_wv, c1_we, c1_weo,
                               wT0, wT1, weoT, qb, kb, vb, ehb, Ab, en, xn, la, tid);

        // P5 (layers 0,1): x = leaky(LN(xn)) -> xsb; e = leaky(en) -> esb
        if (layer < 2) {
            const float* g  = (layer == 0) ? ln0_g : ln1_g;
            const float* be = (layer == 0) ? ln0_b : ln1_b;
            for (int idx = tid; idx < 288; idx += TPB) {
                int j = idx >> 5, c = idx & 31;
                float mu = 0.f;
                #pragma unroll
                for (int t = 0; t < 32; ++t) mu += xn[j * 32 + t];
                mu *= (1.f / 32.f);
                float var = 0.f;
                #pragma unroll
                for (int t = 0; t < 32; ++t) { float d = xn[j * 32 + t] - mu; var = fmaf(d, d, var); }
                var *= (1.f / 32.f);
                float val = (xn[idx] - mu) / sqrtf(var + 1e-5f);
                val = val * g[c] + be[c];
                xsb[j * 40 + c] = f2b((val > 0.f) ? val : 0.01f * val);
            }
            for (int idx = tid; idx < 2592; idx += TPB) {
                int le = idx >> 5, c = idx & 31;
                float v = en[idx];
                esb[le * 40 + c] = f2b((v > 0.f) ? v : 0.01f * v);
            }
            __syncthreads();
        }
    }

    // Finals.  After layer 2 (no post): xn [9,32] f32, en [81,32] f32.
    float* out_x  = out;                       // [36864,10]
    float* out_e  = out + 368640;              // [294912,5]
    float* out_ei = out + 1843200;             // [2,294912]
    float* out_b  = out + 2433024;             // [36864]

    for (int idx = tid; idx < 90; idx += TPB) {         // x @ w_feat
        int j = idx / 10, c = idx - j * 10;
        float acc = 0.f;
        #pragma unroll
        for (int kk = 0; kk < 32; ++kk) acc = fmaf(xn[j * 32 + kk], w_feat[kk * 10 + c], acc);
        out_x[(b * 9 + j) * 10 + c] = acc;
    }
    for (int idx = tid; idx < 360; idx += TPB) {        // masked eattr @ w_eout
        int r = idx / 5, c = idx - r * 5;
        int i = r >> 3, jj = r & 7;
        int j = jj + (jj >= i ? 1 : 0);
        const float* row = &en[(i * 9 + j) * 32];
        float acc = 0.f;
        #pragma unroll
        for (int kk = 0; kk < 32; ++kk) acc = fmaf(row[kk], w_eout[kk * 5 + c], acc);
        out_e[(b * 72 + r) * 5 + c] = acc;
    }
    for (int idx = tid; idx < 72; idx += TPB) {         // edge_index
        int i = idx >> 3, jj = idx & 7;
        int j = jj + (jj >= i ? 1 : 0);
        out_ei[b * 72 + idx]          = (float)(b * 9 + i);
        out_ei[294912 + b * 72 + idx] = (float)(b * 9 + j);
    }
    for (int idx = tid; idx < 9; idx += TPB)            // batch
        out_b[b * 9 + idx] = (float)b;
}

// ---------------------------------------------------------------------------
extern "C" void kernel_launch(void* const* d_in, const int* in_sizes, int n_in,
                              void* d_out, int out_size, void* d_ws, size_t ws_size,
                              hipStream_t stream)
{
    const float* latent  = (const float*)d_in[0];
    const float* w_mlp0  = (const float*)d_in[1];
    const float* b_mlp0  = (const float*)d_in[2];
    const float* w_mlp1  = (const float*)d_in[3];
    const float* b_mlp1  = (const float*)d_in[4];
    const float* w_mlp2  = (const float*)d_in[5];
    const float* b_mlp2  = (const float*)d_in[6];
    const float* w_edges = (const float*)d_in[7];
    const float* b_edges = (const float*)d_in[8];
    const float* w_nodes = (const float*)d_in[9];
    const float* b_nodes = (const float*)d_in[10];
    const float* c0_wq   = (const float*)d_in[11];
    const float* c0_wk   = (const float*)d_in[12];
    const float* c0_wv   = (const float*)d_in[13];
    const float* c0_we   = (const float*)d_in[14];
    const float* c0_weo  = (const float*)d_in[15];
    const float* c1_wq   = (const float*)d_in[16];
    const float* c1_wk   = (const float*)d_in[17];
    const float* c1_wv   = (const float*)d_in[18];
    const float* c1_we   = (const float*)d_in[19];
    const float* c1_weo  = (const float*)d_in[20];
    const float* ln0_g   = (const float*)d_in[21];
    const float* ln0_b   = (const float*)d_in[22];
    const float* ln1_g   = (const float*)d_in[23];
    const float* ln1_b   = (const float*)d_in[24];
    const float* w_feat  = (const float*)d_in[25];
    const float* w_eout  = (const float*)d_in[26];

    // Workspace layout with lifetime overlap (peak 18.3 MB)
    float* ws = (float*)d_ws;
    float* h0 = ws;
    float* el = ws;
    float* h1 = ws + 1658880;
    float* nl = ws + 1658880;
    float* h2 = ws + 2707456;

    float* out = (float*)d_out;

    gemm_act_kernel<<<512, 256, 0, stream>>>(latent, w_mlp0, b_mlp0, h0, 128, 128, 1);
    gemm_act_kernel<<<512, 256, 0, stream>>>(h0, w_mlp1, b_mlp1, h1, 128, 256, 1);
    gemm_act_kernel<<<512, 256, 0, stream>>>(h1, w_mlp2, b_mlp2, h2, 256, 512, 1);
    gemm_act_kernel<<<512, 256, 0, stream>>>(h2, w_edges, b_edges, el, 512, 405, 0);
    gemm_act_kernel<<<512, 256, 0, stream>>>(h2, w_nodes, b_nodes, nl, 512, 117, 0);

    fused_gnn_kernel<<<B_, TPB, 0, stream>>>(nl, el,
        c0_wq, c0_wk, c0_wv, c0_we, c0_weo,
        c1_wq, c1_wk, c1_wv, c1_we, c1_weo,
        ln0_g, ln0_b, ln1_g, ln1_b, w_feat, w_eout, out);
}

// Round 23
// 730.090 us; speedup vs baseline: 1.8863x; 1.2403x over previous
//
#include <hip/hip_runtime.h>
#include <hip/hip_bf16.h>
#include <math.h>

#define B_    4096
#define V_    9
#define N_    (B_*V_)          // 36864 nodes
#define EK_   (B_*V_*(V_-1))   // 294912 kept edges
#define TPB   512

typedef unsigned short ushort_t;
typedef __attribute__((ext_vector_type(8))) short bf16x8;   // 8 bf16 (4 VGPRs)
typedef __attribute__((ext_vector_type(4))) float f32x4;    // 4 f32 acc

__device__ __forceinline__ float b2f(ushort_t u) {
    union { unsigned int i; float f; } x; x.i = ((unsigned int)u) << 16; return x.f;
}
__device__ __forceinline__ ushort_t f2b(float f) {
    union { float f; unsigned int i; } x; x.f = f;
    unsigned int r = x.i + 0x7FFFu + ((x.i >> 16) & 1u);
    return (ushort_t)(r >> 16);
}

// ---------------------------------------------------------------------------
// Register-tiled GEMM for the MLP head: out[M,Nc] = act(A @ W + bias).
// 16 rows/block; A staged TRANSPOSED in LDS (As[k*20+r], pad 20 -> 16B-aligned
// b128 row reads, bank-spread).  Each thread owns one column n with 16 row
// accumulators; per k: 1 coalesced W load + 4 broadcast ds_read_b128 + 16 FMA.
// Replaces the r2-era latency-bound version (1 global load per FMA, ~10 TF).
// ---------------------------------------------------------------------------
__global__ __launch_bounds__(256) void gemm_tile_kernel(
    const float* __restrict__ A, const float* __restrict__ W,
    const float* __restrict__ bias, float* __restrict__ out,
    int K, int Nc, int act)
{
    __shared__ float As[512 * 20];   // max K = 512 -> 40 KB
    const int row0 = blockIdx.x * 16;
    const int tid  = threadIdx.x;

    // stage A transposed: coalesced global read (k fastest), LDS write k*20+r
    for (int idx = tid; idx < 16 * K; idx += 256) {
        int r = idx / K, k = idx - r * K;
        As[k * 20 + r] = A[(row0 + r) * K + k];
    }
    __syncthreads();

    for (int n = tid; n < Nc; n += 256) {
        float acc[16];
        #pragma unroll
        for (int r = 0; r < 16; ++r) acc[r] = 0.f;
        #pragma unroll 4
        for (int k = 0; k < K; ++k) {
            float w = W[k * Nc + n];
            const f32x4* ap = (const f32x4*)&As[k * 20];
            f32x4 a0 = ap[0], a1 = ap[1], a2 = ap[2], a3 = ap[3];
            #pragma unroll
            for (int u = 0; u < 4; ++u) {
                acc[u]      = fmaf(a0[u], w, acc[u]);
                acc[4 + u]  = fmaf(a1[u], w, acc[4 + u]);
                acc[8 + u]  = fmaf(a2[u], w, acc[8 + u]);
                acc[12 + u] = fmaf(a3[u], w, acc[12 + u]);
            }
        }
        float bv = bias[n];
        #pragma unroll
        for (int r = 0; r < 16; ++r) {
            float val = acc[r] + bv;
            if (act == 1) val = tanhf(val);
            out[(row0 + r) * Nc + n] = val;
        }
    }
}

// ---------------------------------------------------------------------------
// MFMA conv layer (byte-identical to round 21 -- measured 524 us, passed).
//   A: lane l -> row (l&15), k = (l>>4)*8 + e
//   B: lane l -> col (l&15), k = (l>>4)*8 + e   (weights staged TRANSPOSED)
//   D: lane l -> col (l&15), row = (l>>4)*4 + r (m89-verified)
// ---------------------------------------------------------------------------
template <int XD, int ED2>
__device__ __forceinline__ void conv_layer(
    ushort_t* xsb, ushort_t* esb,          // [16][40], [96][40] bf16 state
    const float* __restrict__ wq_g, const float* __restrict__ wk_g,
    const float* __restrict__ wv_g, const float* __restrict__ we_g,
    const float* __restrict__ weo_g,
    ushort_t* wT0, ushort_t* wT1,          // [128][40] transposed weights
    ushort_t* weoT,                        // [32][104] transposed weo
    ushort_t* qb, ushort_t* kb, ushort_t* vb,  // [16][132] bf16
    ushort_t* ehb,                         // [96][132] bf16
    ushort_t* Ab,                          // [96][104] bf16 concat A
    float* en, float* xn, float* la, int tid)
{
    const int wv_  = tid >> 6;
    const int lane = tid & 63;
    const int l15  = lane & 15;
    const int kg   = lane >> 4;          // k0 = kg*8

    // S1: stage wq^T, wk^T (zero-pad rows m>=XD)
    for (int idx = tid; idx < 4096; idx += TPB) {
        int m = idx >> 7, n = idx & 127;
        wT0[n * 40 + m] = (m < XD) ? f2b(wq_g[m * 128 + n]) : (ushort_t)0;
        wT1[n * 40 + m] = (m < XD) ? f2b(wk_g[m * 128 + n]) : (ushort_t)0;
    }
    __syncthreads();

    // P1a: q,k = xs @ wq/wk   (16 wave-tasks)
    for (int task = wv_; task < 16; task += 8) {
        int mat = task >> 3, nt = task & 7;
        bf16x8 a = *(const bf16x8*)&xsb[l15 * 40 + kg * 8];
        const ushort_t* wt = mat ? wT1 : wT0;
        bf16x8 bf = *(const bf16x8*)&wt[(nt * 16 + l15) * 40 + kg * 8];
        f32x4 d = {0.f, 0.f, 0.f, 0.f};
        d = __builtin_amdgcn_mfma_f32_16x16x32_bf16(a, bf, d, 0, 0, 0);
        ushort_t* dst = mat ? kb : qb;
        #pragma unroll
        for (int r = 0; r < 4; ++r)
            dst[(kg * 4 + r) * 132 + nt * 16 + l15] = f2b(d[r]);
    }
    __syncthreads();

    // S2: stage wv^T, we^T, weo^T
    for (int idx = tid; idx < 4096; idx += TPB) {
        int m = idx >> 7, n = idx & 127;
        wT0[n * 40 + m] = (m < XD)  ? f2b(wv_g[m * 128 + n]) : (ushort_t)0;
        wT1[n * 40 + m] = (m < ED2) ? f2b(we_g[m * 128 + n]) : (ushort_t)0;
    }
    for (int idx = tid; idx < 3072; idx += TPB) {
        int r = idx >> 5, c = idx & 31;
        weoT[c * 104 + r] = (r < 2 * XD + ED2) ? f2b(weo_g[r * 32 + c]) : (ushort_t)0;
    }
    __syncthreads();

    // P1b: v = xs @ wv (8 tasks) + eh = es @ we (48 tasks)
    for (int task = wv_; task < 56; task += 8) {
        if (task < 8) {
            int nt = task;
            bf16x8 a = *(const bf16x8*)&xsb[l15 * 40 + kg * 8];
            bf16x8 bf = *(const bf16x8*)&wT0[(nt * 16 + l15) * 40 + kg * 8];
            f32x4 d = {0.f, 0.f, 0.f, 0.f};
            d = __builtin_amdgcn_mfma_f32_16x16x32_bf16(a, bf, d, 0, 0, 0);
            #pragma unroll
            for (int r = 0; r < 4; ++r)
                vb[(kg * 4 + r) * 132 + nt * 16 + l15] = f2b(d[r]);
        } else {
            int t2 = task - 8, mt = t2 >> 3, nt = t2 & 7;
            bf16x8 a = *(const bf16x8*)&esb[(mt * 16 + l15) * 40 + kg * 8];
            bf16x8 bf = *(const bf16x8*)&wT1[(nt * 16 + l15) * 40 + kg * 8];
            f32x4 d = {0.f, 0.f, 0.f, 0.f};
            d = __builtin_amdgcn_mfma_f32_16x16x32_bf16(a, bf, d, 0, 0, 0);
            #pragma unroll
            for (int r = 0; r < 4; ++r)
                ehb[(mt * 16 + kg * 4 + r) * 132 + nt * 16 + l15] = f2b(d[r]);
        }
    }
    __syncthreads();

    // P2a: logits[le,h] = (q[dst=j] . (k[src=i]+eh)) / sqrt(32)
    for (int idx = tid; idx < 324; idx += TPB) {
        int le = idx >> 2, h = idx & 3;
        int i = le / 9, j = le - i * 9;
        const ushort_t* qp = &qb[j * 132 + h * 32];
        const ushort_t* kp = &kb[i * 132 + h * 32];
        const ushort_t* ep = &ehb[le * 132 + h * 32];
        float acc = 0.f;
        #pragma unroll
        for (int d = 0; d < 32; ++d)
            acc = fmaf(b2f(qp[d]), b2f(kp[d]) + b2f(ep[d]), acc);
        la[idx] = acc * 0.17677669529663687f;
    }
    __syncthreads();

    // P2b: segment softmax over src i per (dst j, head h)
    for (int s = tid; s < 36; s += TPB) {
        int j = s >> 2, h = s & 3;
        float m = -1e30f;
        #pragma unroll
        for (int i = 0; i < 9; ++i) m = fmaxf(m, la[(i * 9 + j) * 4 + h]);
        float ex[9], sum = 0.f;
        #pragma unroll
        for (int i = 0; i < 9; ++i) { ex[i] = __expf(la[(i * 9 + j) * 4 + h] - m); sum += ex[i]; }
        float inv = 1.f / (sum + 1e-16f);
        #pragma unroll
        for (int i = 0; i < 9; ++i) la[(i * 9 + j) * 4 + h] = ex[i] * inv;
    }
    __syncthreads();

    // P3: aggregation -> xn[j,d];  merged: build concat-A for P4
    for (int idx = tid; idx < 288; idx += TPB) {
        int j = idx >> 5, d = idx & 31;
        float acc = 0.f;
        #pragma unroll
        for (int h = 0; h < 4; ++h)
            #pragma unroll
            for (int i = 0; i < 9; ++i) {
                int le = i * 9 + j;
                acc = fmaf(la[le * 4 + h],
                           b2f(vb[i * 132 + h * 32 + d]) + b2f(ehb[le * 132 + h * 32 + d]), acc);
            }
        xn[idx] = acc * 0.25f;
    }
    for (int idx = tid; idx < 96 * 96; idx += TPB) {
        int le = idx / 96, k = idx - le * 96;
        int i = le / 9, j = le - i * 9;     // le>=81: i<=10 -> zero rows of xsb
        ushort_t v = 0;
        if (XD == 13) {
            if (k < 13)      v = xsb[i * 40 + k];
            else if (k < 26) v = xsb[j * 40 + (k - 13)];
            else if (k < 31) v = esb[le * 40 + (k - 26)];
        } else {
            if (k < 32)      v = xsb[i * 40 + k];
            else if (k < 64) v = xsb[j * 40 + (k - 32)];
            else             v = esb[le * 40 + (k - 64)];
        }
        Ab[le * 104 + k] = v;
    }
    __syncthreads();

    // P4: en = concat(x_src,x_dst,e) @ weo   (12 wave-tasks x KS k-steps)
    const int KS = (XD == 13) ? 1 : 3;
    for (int task = wv_; task < 12; task += 8) {
        int mt = task >> 1, nt = task & 1;
        f32x4 d = {0.f, 0.f, 0.f, 0.f};
        #pragma unroll
        for (int ks = 0; ks < KS; ++ks) {
            bf16x8 a = *(const bf16x8*)&Ab[(mt * 16 + l15) * 104 + ks * 32 + kg * 8];
            bf16x8 bf = *(const bf16x8*)&weoT[(nt * 16 + l15) * 104 + ks * 32 + kg * 8];
            d = __builtin_amdgcn_mfma_f32_16x16x32_bf16(a, bf, d, 0, 0, 0);
        }
        #pragma unroll
        for (int r = 0; r < 4; ++r) {
            int row = mt * 16 + kg * 4 + r;
            if (row < 81) en[row * 32 + nt * 16 + l15] = d[r];
        }
    }
    __syncthreads();
}

// ---------------------------------------------------------------------------
// Fused GNN, MFMA edition (byte-identical to round 21).
// ---------------------------------------------------------------------------
__global__ __launch_bounds__(TPB, 2) void fused_gnn_kernel(
    const float* __restrict__ nl,    // [B, 117]
    const float* __restrict__ el,    // [B, 405]
    const float* __restrict__ c0_wq, const float* __restrict__ c0_wk,
    const float* __restrict__ c0_wv, const float* __restrict__ c0_we,
    const float* __restrict__ c0_weo,
    const float* __restrict__ c1_wq, const float* __restrict__ c1_wk,
    const float* __restrict__ c1_wv, const float* __restrict__ c1_we,
    const float* __restrict__ c1_weo,
    const float* __restrict__ ln0_g, const float* __restrict__ ln0_b,
    const float* __restrict__ ln1_g, const float* __restrict__ ln1_b,
    const float* __restrict__ w_feat, const float* __restrict__ w_eout,
    float* __restrict__ out)
{
    __shared__ __align__(16) ushort_t xsb[16 * 40];     // bf16 x-state (pad rows/cols 0)
    __shared__ __align__(16) ushort_t esb[96 * 40];     // bf16 e-state
    __shared__ __align__(16) ushort_t wT0[128 * 40];    // W^T staging
    __shared__ __align__(16) ushort_t wT1[128 * 40];
    __shared__ __align__(16) ushort_t weoT[32 * 104];
    __shared__ __align__(16) ushort_t qb[16 * 132];
    __shared__ __align__(16) ushort_t kb[16 * 132];
    __shared__ __align__(16) ushort_t vb[16 * 132];
    __shared__ __align__(16) ushort_t ehb[96 * 132];
    __shared__ __align__(16) ushort_t Ab[96 * 104];
    __shared__ float en[81 * 32];
    __shared__ float la[324];
    __shared__ float xn[288];

    const int b   = blockIdx.x;
    const int tid = threadIdx.x;

    // zero padded state buffers, then stage layer-0 inputs
    for (int idx = tid; idx < 16 * 40; idx += TPB) xsb[idx] = 0;
    for (int idx = tid; idx < 96 * 40; idx += TPB) esb[idx] = 0;
    __syncthreads();
    for (int idx = tid; idx < 117; idx += TPB) {
        int node = idx / 13, m = idx - node * 13;
        xsb[node * 40 + m] = f2b(nl[b * 117 + idx]);
    }
    for (int idx = tid; idx < 405; idx += TPB) {
        int le = idx / 5, c = idx - le * 5;
        int i = le / 9, j = le - i * 9;
        esb[le * 40 + c] = f2b(0.5f * (el[b * 405 + c * 81 + i * 9 + j] +
                                       el[b * 405 + c * 81 + j * 9 + i]));
    }
    __syncthreads();

    for (int layer = 0; layer < 3; ++layer) {
        if (layer == 0)
            conv_layer<13, 5>(xsb, esb, c0_wq, c0_wk, c0_wv, c0_we, c0_weo,
                              wT0, wT1, weoT, qb, kb, vb, ehb, Ab, en, xn, la, tid);
        else
            conv_layer<32, 32>(xsb, esb, c1_wq, c1_wk, c1_wv, c1_we, c1_weo,
                               wT0, wT1, weoT, qb, kb, vb, ehb, Ab, en, xn, la, tid);

        // P5 (layers 0,1): x = leaky(LN(xn)) -> xsb; e = leaky(en) -> esb
        if (layer < 2) {
            const float* g  = (layer == 0) ? ln0_g : ln1_g;
            const float* be = (layer == 0) ? ln0_b : ln1_b;
            for (int idx = tid; idx < 288; idx += TPB) {
                int j = idx >> 5, c = idx & 31;
                float mu = 0.f;
                #pragma unroll
                for (int t = 0; t < 32; ++t) mu += xn[j * 32 + t];
                mu *= (1.f / 32.f);
                float var = 0.f;
                #pragma unroll
                for (int t = 0; t < 32; ++t) { float d = xn[j * 32 + t] - mu; var = fmaf(d, d, var); }
                var *= (1.f / 32.f);
                float val = (xn[idx] - mu) / sqrtf(var + 1e-5f);
                val = val * g[c] + be[c];
                xsb[j * 40 + c] = f2b((val > 0.f) ? val : 0.01f * val);
            }
            for (int idx = tid; idx < 2592; idx += TPB) {
                int le = idx >> 5, c = idx & 31;
                float v = en[idx];
                esb[le * 40 + c] = f2b((v > 0.f) ? v : 0.01f * v);
            }
            __syncthreads();
        }
    }

    // Finals.  After layer 2 (no post): xn [9,32] f32, en [81,32] f32.
    float* out_x  = out;                       // [36864,10]
    float* out_e  = out + 368640;              // [294912,5]
    float* out_ei = out + 1843200;             // [2,294912]
    float* out_b  = out + 2433024;             // [36864]

    for (int idx = tid; idx < 90; idx += TPB) {         // x @ w_feat
        int j = idx / 10, c = idx - j * 10;
        float acc = 0.f;
        #pragma unroll
        for (int kk = 0; kk < 32; ++kk) acc = fmaf(xn[j * 32 + kk], w_feat[kk * 10 + c], acc);
        out_x[(b * 9 + j) * 10 + c] = acc;
    }
    for (int idx = tid; idx < 360; idx += TPB) {        // masked eattr @ w_eout
        int r = idx / 5, c = idx - r * 5;
        int i = r >> 3, jj = r & 7;
        int j = jj + (jj >= i ? 1 : 0);
        const float* row = &en[(i * 9 + j) * 32];
        float acc = 0.f;
        #pragma unroll
        for (int kk = 0; kk < 32; ++kk) acc = fmaf(row[kk], w_eout[kk * 5 + c], acc);
        out_e[(b * 72 + r) * 5 + c] = acc;
    }
    for (int idx = tid; idx < 72; idx += TPB) {         // edge_index
        int i = idx >> 3, jj = idx & 7;
        int j = jj + (jj >= i ? 1 : 0);
        out_ei[b * 72 + idx]          = (float)(b * 9 + i);
        out_ei[294912 + b * 72 + idx] = (float)(b * 9 + j);
    }
    for (int idx = tid; idx < 9; idx += TPB)            // batch
        out_b[b * 9 + idx] = (float)b;
}

// ---------------------------------------------------------------------------
extern "C" void kernel_launch(void* const* d_in, const int* in_sizes, int n_in,
                              void* d_out, int out_size, void* d_ws, size_t ws_size,
                              hipStream_t stream)
{
    const float* latent  = (const float*)d_in[0];
    const float* w_mlp0  = (const float*)d_in[1];
    const float* b_mlp0  = (const float*)d_in[2];
    const float* w_mlp1  = (const float*)d_in[3];
    const float* b_mlp1  = (const float*)d_in[4];
    const float* w_mlp2  = (const float*)d_in[5];
    const float* b_mlp2  = (const float*)d_in[6];
    const float* w_edges = (const float*)d_in[7];
    const float* b_edges = (const float*)d_in[8];
    const float* w_nodes = (const float*)d_in[9];
    const float* b_nodes = (const float*)d_in[10];
    const float* c0_wq   = (const float*)d_in[11];
    const float* c0_wk   = (const float*)d_in[12];
    const float* c0_wv   = (const float*)d_in[13];
    const float* c0_we   = (const float*)d_in[14];
    const float* c0_weo  = (const float*)d_in[15];
    const float* c1_wq   = (const float*)d_in[16];
    const float* c1_wk   = (const float*)d_in[17];
    const float* c1_wv   = (const float*)d_in[18];
    const float* c1_we   = (const float*)d_in[19];
    const float* c1_weo  = (const float*)d_in[20];
    const float* ln0_g   = (const float*)d_in[21];
    const float* ln0_b   = (const float*)d_in[22];
    const float* ln1_g   = (const float*)d_in[23];
    const float* ln1_b   = (const float*)d_in[24];
    const float* w_feat  = (const float*)d_in[25];
    const float* w_eout  = (const float*)d_in[26];

    // Workspace layout with lifetime overlap (peak 18.3 MB)
    float* ws = (float*)d_ws;
    float* h0 = ws;
    float* el = ws;
    float* h1 = ws + 1658880;
    float* nl = ws + 1658880;
    float* h2 = ws + 2707456;

    float* out = (float*)d_out;

    gemm_tile_kernel<<<256, 256, 0, stream>>>(latent, w_mlp0, b_mlp0, h0, 128, 128, 1);
    gemm_tile_kernel<<<256, 256, 0, stream>>>(h0, w_mlp1, b_mlp1, h1, 128, 256, 1);
    gemm_tile_kernel<<<256, 256, 0, stream>>>(h1, w_mlp2, b_mlp2, h2, 256, 512, 1);
    gemm_tile_kernel<<<256, 256, 0, stream>>>(h2, w_edges, b_edges, el, 512, 405, 0);
    gemm_tile_kernel<<<256, 256, 0, stream>>>(h2, w_nodes, b_nodes, nl, 512, 117, 0);

    fused_gnn_kernel<<<B_, TPB, 0, stream>>>(nl, el,
        c0_wq, c0_wk, c0_wv, c0_we, c0_weo,
        c1_wq, c1_wk, c1_wv, c1_we, c1_weo,
        ln0_g, ln0_b, ln1_g, ln1_b, w_feat, w_eout, out);
}

// Round 24
// 633.065 us; speedup vs baseline: 2.1754x; 1.1533x over previous
//
#include <hip/hip_runtime.h>
#include <hip/hip_bf16.h>
#include <math.h>

#define B_    4096
#define V_    9
#define N_    (B_*V_)          // 36864 nodes
#define EK_   (B_*V_*(V_-1))   // 294912 kept edges
#define TPB   512

typedef unsigned short ushort_t;
typedef __attribute__((ext_vector_type(8))) short bf16x8;   // 8 bf16 (4 VGPRs)
typedef __attribute__((ext_vector_type(4))) float f32x4;    // 4 f32 acc / 16B chunk

__device__ __forceinline__ float b2f(ushort_t u) {
    union { unsigned int i; float f; } x; x.i = ((unsigned int)u) << 16; return x.f;
}
__device__ __forceinline__ ushort_t f2b(float f) {
    union { float f; unsigned int i; } x; x.f = f;
    unsigned int r = x.i + 0x7FFFu + ((x.i >> 16) & 1u);
    return (ushort_t)(r >> 16);
}

// ---------------------------------------------------------------------------
// Register-tiled GEMM for the MLP head (measured r23: chain ~200 us)
// ---------------------------------------------------------------------------
__global__ __launch_bounds__(256) void gemm_tile_kernel(
    const float* __restrict__ A, const float* __restrict__ W,
    const float* __restrict__ bias, float* __restrict__ out,
    int K, int Nc, int act)
{
    __shared__ float As[512 * 20];   // max K = 512 -> 40 KB
    const int row0 = blockIdx.x * 16;
    const int tid  = threadIdx.x;

    for (int idx = tid; idx < 16 * K; idx += 256) {
        int r = idx / K, k = idx - r * K;
        As[k * 20 + r] = A[(row0 + r) * K + k];
    }
    __syncthreads();

    for (int n = tid; n < Nc; n += 256) {
        float acc[16];
        #pragma unroll
        for (int r = 0; r < 16; ++r) acc[r] = 0.f;
        #pragma unroll 4
        for (int k = 0; k < K; ++k) {
            float w = W[k * Nc + n];
            const f32x4* ap = (const f32x4*)&As[k * 20];
            f32x4 a0 = ap[0], a1 = ap[1], a2 = ap[2], a3 = ap[3];
            #pragma unroll
            for (int u = 0; u < 4; ++u) {
                acc[u]      = fmaf(a0[u], w, acc[u]);
                acc[4 + u]  = fmaf(a1[u], w, acc[4 + u]);
                acc[8 + u]  = fmaf(a2[u], w, acc[8 + u]);
                acc[12 + u] = fmaf(a3[u], w, acc[12 + u]);
            }
        }
        float bv = bias[n];
        #pragma unroll
        for (int r = 0; r < 16; ++r) {
            float val = acc[r] + bv;
            if (act == 1) val = tanhf(val);
            out[(row0 + r) * Nc + n] = val;
        }
    }
}

// ---------------------------------------------------------------------------
// One-shot weight prep: transpose + bf16-convert + zero-pad all conv weights
// into workspace.  Layout (ushort offsets):
//   [0..40960): 8 x [128][40] qkv/e buffers  (c0: wq,wk,wv,we; c1: wq,wk,wv,we)
//   [40960..47616): 2 x [32][104] weoT       (c0, c1)
// Eliminates the 4096x-redundant per-block f32 load+cvt+transpose staging.
// ---------------------------------------------------------------------------
__global__ __launch_bounds__(256) void prep_weights_kernel(
    const float* __restrict__ c0_wq, const float* __restrict__ c0_wk,
    const float* __restrict__ c0_wv, const float* __restrict__ c0_we,
    const float* __restrict__ c0_weo,
    const float* __restrict__ c1_wq, const float* __restrict__ c1_wk,
    const float* __restrict__ c1_wv, const float* __restrict__ c1_we,
    const float* __restrict__ c1_weo,
    ushort_t* __restrict__ wb)
{
    int idx = blockIdx.x * 256 + threadIdx.x;
    if (idx < 40960) {
        int buf = idx / 5120, r = idx - buf * 5120;
        int n = r / 40, m = r - n * 40;
        const float* src; int K;
        switch (buf) {
            case 0: src = c0_wq; K = 13; break;
            case 1: src = c0_wk; K = 13; break;
            case 2: src = c0_wv; K = 13; break;
            case 3: src = c0_we; K = 5;  break;
            case 4: src = c1_wq; K = 32; break;
            case 5: src = c1_wk; K = 32; break;
            case 6: src = c1_wv; K = 32; break;
            default: src = c1_we; K = 32; break;
        }
        wb[idx] = (m < K) ? f2b(src[m * 128 + n]) : (ushort_t)0;
    } else if (idx < 47616) {
        int r2 = idx - 40960;
        int which = r2 / 3328, r = r2 - which * 3328;
        int c = r / 104, row = r - c * 104;
        const float* src = which ? c1_weo : c0_weo;
        int R = which ? 96 : 31;
        wb[idx] = (row < R) ? f2b(src[row * 32 + c]) : (ushort_t)0;
    }
}

// ---------------------------------------------------------------------------
// MFMA conv layer.  Fragment math byte-identical to r21 (measured 524 us);
// staging replaced by 16B copies of the precomputed bf16 weight images.
//   A: lane l -> row (l&15), k = (l>>4)*8 + e
//   B: lane l -> col (l&15), k = (l>>4)*8 + e
//   D: lane l -> col (l&15), row = (l>>4)*4 + r (m89-verified)
// ---------------------------------------------------------------------------
template <int XD, int ED2>
__device__ __forceinline__ void conv_layer(
    ushort_t* xsb, ushort_t* esb,          // [16][40], [96][40] bf16 state
    const ushort_t* __restrict__ wq_p, const ushort_t* __restrict__ wk_p,
    const ushort_t* __restrict__ wv_p, const ushort_t* __restrict__ we_p,
    const ushort_t* __restrict__ weo_p,    // precomputed bf16 images
    ushort_t* wT0, ushort_t* wT1,          // [128][40] LDS
    ushort_t* weoT,                        // [32][104] LDS
    ushort_t* qb, ushort_t* kb, ushort_t* vb,  // [16][132] bf16
    ushort_t* ehb,                         // [96][132] bf16
    ushort_t* Ab,                          // [96][104] bf16 concat A
    float* en, float* xn, float* la, int tid)
{
    const int wv_  = tid >> 6;
    const int lane = tid & 63;
    const int l15  = lane & 15;
    const int kg   = lane >> 4;          // k0 = kg*8

    // S1: copy wq^T, wk^T images (640 x 16B each)
    for (int idx = tid; idx < 640; idx += TPB) {
        ((f32x4*)wT0)[idx] = ((const f32x4*)wq_p)[idx];
        ((f32x4*)wT1)[idx] = ((const f32x4*)wk_p)[idx];
    }
    __syncthreads();

    // P1a: q,k = xs @ wq/wk   (16 wave-tasks)
    for (int task = wv_; task < 16; task += 8) {
        int mat = task >> 3, nt = task & 7;
        bf16x8 a = *(const bf16x8*)&xsb[l15 * 40 + kg * 8];
        const ushort_t* wt = mat ? wT1 : wT0;
        bf16x8 bf = *(const bf16x8*)&wt[(nt * 16 + l15) * 40 + kg * 8];
        f32x4 d = {0.f, 0.f, 0.f, 0.f};
        d = __builtin_amdgcn_mfma_f32_16x16x32_bf16(a, bf, d, 0, 0, 0);
        ushort_t* dst = mat ? kb : qb;
        #pragma unroll
        for (int r = 0; r < 4; ++r)
            dst[(kg * 4 + r) * 132 + nt * 16 + l15] = f2b(d[r]);
    }
    __syncthreads();

    // S2: copy wv^T, we^T, weo^T images
    for (int idx = tid; idx < 640; idx += TPB) {
        ((f32x4*)wT0)[idx] = ((const f32x4*)wv_p)[idx];
        ((f32x4*)wT1)[idx] = ((const f32x4*)we_p)[idx];
    }
    for (int idx = tid; idx < 416; idx += TPB)
        ((f32x4*)weoT)[idx] = ((const f32x4*)weo_p)[idx];
    __syncthreads();

    // P1b: v = xs @ wv (8 tasks) + eh = es @ we (48 tasks)
    for (int task = wv_; task < 56; task += 8) {
        if (task < 8) {
            int nt = task;
            bf16x8 a = *(const bf16x8*)&xsb[l15 * 40 + kg * 8];
            bf16x8 bf = *(const bf16x8*)&wT0[(nt * 16 + l15) * 40 + kg * 8];
            f32x4 d = {0.f, 0.f, 0.f, 0.f};
            d = __builtin_amdgcn_mfma_f32_16x16x32_bf16(a, bf, d, 0, 0, 0);
            #pragma unroll
            for (int r = 0; r < 4; ++r)
                vb[(kg * 4 + r) * 132 + nt * 16 + l15] = f2b(d[r]);
        } else {
            int t2 = task - 8, mt = t2 >> 3, nt = t2 & 7;
            bf16x8 a = *(const bf16x8*)&esb[(mt * 16 + l15) * 40 + kg * 8];
            bf16x8 bf = *(const bf16x8*)&wT1[(nt * 16 + l15) * 40 + kg * 8];
            f32x4 d = {0.f, 0.f, 0.f, 0.f};
            d = __builtin_amdgcn_mfma_f32_16x16x32_bf16(a, bf, d, 0, 0, 0);
            #pragma unroll
            for (int r = 0; r < 4; ++r)
                ehb[(mt * 16 + kg * 4 + r) * 132 + nt * 16 + l15] = f2b(d[r]);
        }
    }
    __syncthreads();

    // P2a: logits[le,h] = (q[dst=j] . (k[src=i]+eh)) / sqrt(32)
    for (int idx = tid; idx < 324; idx += TPB) {
        int le = idx >> 2, h = idx & 3;
        int i = le / 9, j = le - i * 9;
        const ushort_t* qp = &qb[j * 132 + h * 32];
        const ushort_t* kp = &kb[i * 132 + h * 32];
        const ushort_t* ep = &ehb[le * 132 + h * 32];
        float acc = 0.f;
        #pragma unroll
        for (int d = 0; d < 32; ++d)
            acc = fmaf(b2f(qp[d]), b2f(kp[d]) + b2f(ep[d]), acc);
        la[idx] = acc * 0.17677669529663687f;
    }
    __syncthreads();

    // P2b: segment softmax over src i per (dst j, head h)
    for (int s = tid; s < 36; s += TPB) {
        int j = s >> 2, h = s & 3;
        float m = -1e30f;
        #pragma unroll
        for (int i = 0; i < 9; ++i) m = fmaxf(m, la[(i * 9 + j) * 4 + h]);
        float ex[9], sum = 0.f;
        #pragma unroll
        for (int i = 0; i < 9; ++i) { ex[i] = __expf(la[(i * 9 + j) * 4 + h] - m); sum += ex[i]; }
        float inv = 1.f / (sum + 1e-16f);
        #pragma unroll
        for (int i = 0; i < 9; ++i) la[(i * 9 + j) * 4 + h] = ex[i] * inv;
    }
    __syncthreads();

    // P3: aggregation -> xn[j,d];  merged: build concat-A for P4
    for (int idx = tid; idx < 288; idx += TPB) {
        int j = idx >> 5, d = idx & 31;
        float acc = 0.f;
        #pragma unroll
        for (int h = 0; h < 4; ++h)
            #pragma unroll
            for (int i = 0; i < 9; ++i) {
                int le = i * 9 + j;
                acc = fmaf(la[le * 4 + h],
                           b2f(vb[i * 132 + h * 32 + d]) + b2f(ehb[le * 132 + h * 32 + d]), acc);
            }
        xn[idx] = acc * 0.25f;
    }
    for (int idx = tid; idx < 96 * 96; idx += TPB) {
        int le = idx / 96, k = idx - le * 96;
        int i = le / 9, j = le - i * 9;     // le>=81: i<=10 -> zero rows of xsb
        ushort_t v = 0;
        if (XD == 13) {
            if (k < 13)      v = xsb[i * 40 + k];
            else if (k < 26) v = xsb[j * 40 + (k - 13)];
            else if (k < 31) v = esb[le * 40 + (k - 26)];
        } else {
            if (k < 32)      v = xsb[i * 40 + k];
            else if (k < 64) v = xsb[j * 40 + (k - 32)];
            else             v = esb[le * 40 + (k - 64)];
        }
        Ab[le * 104 + k] = v;
    }
    __syncthreads();

    // P4: en = concat(x_src,x_dst,e) @ weo   (12 wave-tasks x KS k-steps)
    const int KS = (XD == 13) ? 1 : 3;
    for (int task = wv_; task < 12; task += 8) {
        int mt = task >> 1, nt = task & 1;
        f32x4 d = {0.f, 0.f, 0.f, 0.f};
        #pragma unroll
        for (int ks = 0; ks < KS; ++ks) {
            bf16x8 a = *(const bf16x8*)&Ab[(mt * 16 + l15) * 104 + ks * 32 + kg * 8];
            bf16x8 bf = *(const bf16x8*)&weoT[(nt * 16 + l15) * 104 + ks * 32 + kg * 8];
            d = __builtin_amdgcn_mfma_f32_16x16x32_bf16(a, bf, d, 0, 0, 0);
        }
        #pragma unroll
        for (int r = 0; r < 4; ++r) {
            int row = mt * 16 + kg * 4 + r;
            if (row < 81) en[row * 32 + nt * 16 + l15] = d[r];
        }
    }
    __syncthreads();
}

// ---------------------------------------------------------------------------
// Fused GNN, MFMA edition with precomputed weights.
// ---------------------------------------------------------------------------
__global__ __launch_bounds__(TPB, 2) void fused_gnn_kernel(
    const float* __restrict__ nl,    // [B, 117]
    const float* __restrict__ el,    // [B, 405]
    const ushort_t* __restrict__ wb, // precomputed bf16 weight images
    const float* __restrict__ ln0_g, const float* __restrict__ ln0_b,
    const float* __restrict__ ln1_g, const float* __restrict__ ln1_b,
    const float* __restrict__ w_feat, const float* __restrict__ w_eout,
    float* __restrict__ out)
{
    __shared__ __align__(16) ushort_t xsb[16 * 40];
    __shared__ __align__(16) ushort_t esb[96 * 40];
    __shared__ __align__(16) ushort_t wT0[128 * 40];
    __shared__ __align__(16) ushort_t wT1[128 * 40];
    __shared__ __align__(16) ushort_t weoT[32 * 104];
    __shared__ __align__(16) ushort_t qb[16 * 132];
    __shared__ __align__(16) ushort_t kb[16 * 132];
    __shared__ __align__(16) ushort_t vb[16 * 132];
    __shared__ __align__(16) ushort_t ehb[96 * 132];
    __shared__ __align__(16) ushort_t Ab[96 * 104];
    __shared__ float en[81 * 32];
    __shared__ float la[324];
    __shared__ float xn[288];

    const int b   = blockIdx.x;
    const int tid = threadIdx.x;

    // zero padded state buffers, then stage layer-0 inputs
    for (int idx = tid; idx < 16 * 40; idx += TPB) xsb[idx] = 0;
    for (int idx = tid; idx < 96 * 40; idx += TPB) esb[idx] = 0;
    __syncthreads();
    for (int idx = tid; idx < 117; idx += TPB) {
        int node = idx / 13, m = idx - node * 13;
        xsb[node * 40 + m] = f2b(nl[b * 117 + idx]);
    }
    for (int idx = tid; idx < 405; idx += TPB) {
        int le = idx / 5, c = idx - le * 5;
        int i = le / 9, j = le - i * 9;
        esb[le * 40 + c] = f2b(0.5f * (el[b * 405 + c * 81 + i * 9 + j] +
                                       el[b * 405 + c * 81 + j * 9 + i]));
    }
    __syncthreads();

    for (int layer = 0; layer < 3; ++layer) {
        if (layer == 0)
            conv_layer<13, 5>(xsb, esb,
                              wb + 0, wb + 5120, wb + 10240, wb + 15360, wb + 40960,
                              wT0, wT1, weoT, qb, kb, vb, ehb, Ab, en, xn, la, tid);
        else
            conv_layer<32, 32>(xsb, esb,
                               wb + 20480, wb + 25600, wb + 30720, wb + 35840, wb + 44288,
                               wT0, wT1, weoT, qb, kb, vb, ehb, Ab, en, xn, la, tid);

        // P5 (layers 0,1): x = leaky(LN(xn)) -> xsb; e = leaky(en) -> esb
        if (layer < 2) {
            const float* g  = (layer == 0) ? ln0_g : ln1_g;
            const float* be = (layer == 0) ? ln0_b : ln1_b;
            for (int idx = tid; idx < 288; idx += TPB) {
                int j = idx >> 5, c = idx & 31;
                float mu = 0.f;
                #pragma unroll
                for (int t = 0; t < 32; ++t) mu += xn[j * 32 + t];
                mu *= (1.f / 32.f);
                float var = 0.f;
                #pragma unroll
                for (int t = 0; t < 32; ++t) { float d = xn[j * 32 + t] - mu; var = fmaf(d, d, var); }
                var *= (1.f / 32.f);
                float val = (xn[idx] - mu) / sqrtf(var + 1e-5f);
                val = val * g[c] + be[c];
                xsb[j * 40 + c] = f2b((val > 0.f) ? val : 0.01f * val);
            }
            for (int idx = tid; idx < 2592; idx += TPB) {
                int le = idx >> 5, c = idx & 31;
                float v = en[idx];
                esb[le * 40 + c] = f2b((v > 0.f) ? v : 0.01f * v);
            }
            __syncthreads();
        }
    }

    // Finals.  After layer 2 (no post): xn [9,32] f32, en [81,32] f32.
    float* out_x  = out;                       // [36864,10]
    float* out_e  = out + 368640;              // [294912,5]
    float* out_ei = out + 1843200;             // [2,294912]
    float* out_b  = out + 2433024;             // [36864]

    for (int idx = tid; idx < 90; idx += TPB) {         // x @ w_feat
        int j = idx / 10, c = idx - j * 10;
        float acc = 0.f;
        #pragma unroll
        for (int kk = 0; kk < 32; ++kk) acc = fmaf(xn[j * 32 + kk], w_feat[kk * 10 + c], acc);
        out_x[(b * 9 + j) * 10 + c] = acc;
    }
    for (int idx = tid; idx < 360; idx += TPB) {        // masked eattr @ w_eout
        int r = idx / 5, c = idx - r * 5;
        int i = r >> 3, jj = r & 7;
        int j = jj + (jj >= i ? 1 : 0);
        const float* row = &en[(i * 9 + j) * 32];
        float acc = 0.f;
        #pragma unroll
        for (int kk = 0; kk < 32; ++kk) acc = fmaf(row[kk], w_eout[kk * 5 + c], acc);
        out_e[(b * 72 + r) * 5 + c] = acc;
    }
    for (int idx = tid; idx < 72; idx += TPB) {         // edge_index
        int i = idx >> 3, jj = idx & 7;
        int j = jj + (jj >= i ? 1 : 0);
        out_ei[b * 72 + idx]          = (float)(b * 9 + i);
        out_ei[294912 + b * 72 + idx] = (float)(b * 9 + j);
    }
    for (int idx = tid; idx < 9; idx += TPB)            // batch
        out_b[b * 9 + idx] = (float)b;
}

// ---------------------------------------------------------------------------
extern "C" void kernel_launch(void* const* d_in, const int* in_sizes, int n_in,
                              void* d_out, int out_size, void* d_ws, size_t ws_size,
                              hipStream_t stream)
{
    const float* latent  = (const float*)d_in[0];
    const float* w_mlp0  = (const float*)d_in[1];
    const float* b_mlp0  = (const float*)d_in[2];
    const float* w_mlp1  = (const float*)d_in[3];
    const float* b_mlp1  = (const float*)d_in[4];
    const float* w_mlp2  = (const float*)d_in[5];
    const float* b_mlp2  = (const float*)d_in[6];
    const float* w_edges = (const float*)d_in[7];
    const float* b_edges = (const float*)d_in[8];
    const float* w_nodes = (const float*)d_in[9];
    const float* b_nodes = (const float*)d_in[10];
    const float* c0_wq   = (const float*)d_in[11];
    const float* c0_wk   = (const float*)d_in[12];
    const float* c0_wv   = (const float*)d_in[13];
    const float* c0_we   = (const float*)d_in[14];
    const float* c0_weo  = (const float*)d_in[15];
    const float* c1_wq   = (const float*)d_in[16];
    const float* c1_wk   = (const float*)d_in[17];
    const float* c1_wv   = (const float*)d_in[18];
    const float* c1_we   = (const float*)d_in[19];
    const float* c1_weo  = (const float*)d_in[20];
    const float* ln0_g   = (const float*)d_in[21];
    const float* ln0_b   = (const float*)d_in[22];
    const float* ln1_g   = (const float*)d_in[23];
    const float* ln1_b   = (const float*)d_in[24];
    const float* w_feat  = (const float*)d_in[25];
    const float* w_eout  = (const float*)d_in[26];

    // Workspace: MLP intermediates (peak 4,804,608 f32 = 18.3 MB) + 95 KB weights
    float* ws = (float*)d_ws;
    float* h0 = ws;
    float* el = ws;
    float* h1 = ws + 1658880;
    float* nl = ws + 1658880;
    float* h2 = ws + 2707456;
    ushort_t* wb = (ushort_t*)(ws + 4804608);   // 47616 ush = 95232 B

    float* out = (float*)d_out;

    prep_weights_kernel<<<187, 256, 0, stream>>>(
        c0_wq, c0_wk, c0_wv, c0_we, c0_weo,
        c1_wq, c1_wk, c1_wv, c1_we, c1_weo, wb);

    gemm_tile_kernel<<<256, 256, 0, stream>>>(latent, w_mlp0, b_mlp0, h0, 128, 128, 1);
    gemm_tile_kernel<<<256, 256, 0, stream>>>(h0, w_mlp1, b_mlp1, h1, 128, 256, 1);
    gemm_tile_kernel<<<256, 256, 0, stream>>>(h1, w_mlp2, b_mlp2, h2, 256, 512, 1);
    gemm_tile_kernel<<<256, 256, 0, stream>>>(h2, w_edges, b_edges, el, 512, 405, 0);
    gemm_tile_kernel<<<256, 256, 0, stream>>>(h2, w_nodes, b_nodes, nl, 512, 117, 0);

    fused_gnn_kernel<<<B_, TPB, 0, stream>>>(nl, el, wb,
        ln0_g, ln0_b, ln1_g, ln1_b, w_feat, w_eout, out);
}

// Round 28
// 423.357 us; speedup vs baseline: 3.2529x; 1.4953x over previous
//
#include <hip/hip_runtime.h>
#include <hip/hip_bf16.h>
#include <math.h>

#define B_    4096
#define V_    9
#define N_    (B_*V_)          // 36864 nodes
#define EK_   (B_*V_*(V_-1))   // 294912 kept edges
#define TPB   512

typedef unsigned short ushort_t;
typedef __attribute__((ext_vector_type(8))) short bf16x8;   // 8 bf16 (4 VGPRs)
typedef __attribute__((ext_vector_type(4))) float f32x4;    // 4 f32 acc / 16B chunk

__device__ __forceinline__ float b2f(ushort_t u) {
    union { unsigned int i; float f; } x; x.i = ((unsigned int)u) << 16; return x.f;
}
__device__ __forceinline__ ushort_t f2b(float f) {
    union { float f; unsigned int i; } x; x.f = f;
    unsigned int r = x.i + 0x7FFFu + ((x.i >> 16) & 1u);
    return (ushort_t)(r >> 16);
}

// ---------------------------------------------------------------------------
// Register-tiled GEMM for the MLP head (measured r23/r24: chain ~200 us)
// ---------------------------------------------------------------------------
__global__ __launch_bounds__(256) void gemm_tile_kernel(
    const float* __restrict__ A, const float* __restrict__ W,
    const float* __restrict__ bias, float* __restrict__ out,
    int K, int Nc, int act)
{
    __shared__ float As[512 * 20];
    const int row0 = blockIdx.x * 16;
    const int tid  = threadIdx.x;

    for (int idx = tid; idx < 16 * K; idx += 256) {
        int r = idx / K, k = idx - r * K;
        As[k * 20 + r] = A[(row0 + r) * K + k];
    }
    __syncthreads();

    for (int n = tid; n < Nc; n += 256) {
        float acc[16];
        #pragma unroll
        for (int r = 0; r < 16; ++r) acc[r] = 0.f;
        #pragma unroll 4
        for (int k = 0; k < K; ++k) {
            float w = W[k * Nc + n];
            const f32x4* ap = (const f32x4*)&As[k * 20];
            f32x4 a0 = ap[0], a1 = ap[1], a2 = ap[2], a3 = ap[3];
            #pragma unroll
            for (int u = 0; u < 4; ++u) {
                acc[u]      = fmaf(a0[u], w, acc[u]);
                acc[4 + u]  = fmaf(a1[u], w, acc[4 + u]);
                acc[8 + u]  = fmaf(a2[u], w, acc[8 + u]);
                acc[12 + u] = fmaf(a3[u], w, acc[12 + u]);
            }
        }
        float bv = bias[n];
        #pragma unroll
        for (int r = 0; r < 16; ++r) {
            float val = acc[r] + bv;
            if (act == 1) val = tanhf(val);
            out[(row0 + r) * Nc + n] = val;
        }
    }
}

// ---------------------------------------------------------------------------
// One-shot weight prep.  Layout (ushort offsets):
//   [0..40960): 8 x [128][40] qkv/e B-images (c0: wq,wk,wv,we; c1: same)
//   [40960..47616): 2 x [32][104] weo B-images
// Layer-0 weo is ROW-REMAPPED to padded boundaries so P4 A-frags read
// xsb/esb directly (16B-aligned): rows 0..12=x_i w, 16..28=x_j w,
// 32..36=e w, rest 0.
// ---------------------------------------------------------------------------
__global__ __launch_bounds__(256) void prep_weights_kernel(
    const float* __restrict__ c0_wq, const float* __restrict__ c0_wk,
    const float* __restrict__ c0_wv, const float* __restrict__ c0_we,
    const float* __restrict__ c0_weo,
    const float* __restrict__ c1_wq, const float* __restrict__ c1_wk,
    const float* __restrict__ c1_wv, const float* __restrict__ c1_we,
    const float* __restrict__ c1_weo,
    ushort_t* __restrict__ wb)
{
    int idx = blockIdx.x * 256 + threadIdx.x;
    if (idx < 40960) {
        int buf = idx / 5120, r = idx - buf * 5120;
        int n = r / 40, m = r - n * 40;
        const float* src; int K;
        switch (buf) {
            case 0: src = c0_wq; K = 13; break;
            case 1: src = c0_wk; K = 13; break;
            case 2: src = c0_wv; K = 13; break;
            case 3: src = c0_we; K = 5;  break;
            case 4: src = c1_wq; K = 32; break;
            case 5: src = c1_wk; K = 32; break;
            case 6: src = c1_wv; K = 32; break;
            default: src = c1_we; K = 32; break;
        }
        wb[idx] = (m < K) ? f2b(src[m * 128 + n]) : (ushort_t)0;
    } else if (idx < 47616) {
        int r2 = idx - 40960;
        int which = r2 / 3328, r = r2 - which * 3328;
        int c = r / 104, row = r - c * 104;
        float v = 0.f;
        if (which) {
            if (row < 96) v = c1_weo[row * 32 + c];
        } else {
            if (row < 13)                    v = c0_weo[row * 32 + c];
            else if (row >= 16 && row < 29)  v = c0_weo[(13 + row - 16) * 32 + c];
            else if (row >= 32 && row < 37)  v = c0_weo[(26 + row - 32) * 32 + c];
        }
        wb[idx] = f2b(v);
    }
}

// ---------------------------------------------------------------------------
// MFMA conv layer, 2-blocks/CU edition: B-fragments read DIRECTLY from the
// global bf16 weight images (L2-resident, no LDS staging); A-fragments for
// P4 read xsb/esb directly (Ab concat buffer eliminated via weo row remap).
//   A: lane l -> row (l&15), k = (l>>4)*8 + e
//   B: lane l -> col (l&15), k = (l>>4)*8 + e
//   D: lane l -> col (l&15), row = (l>>4)*4 + r (m89-verified)
// Aliases: en (f32) -> ehb (dead after P3); xn (f32) -> qb (dead after P2a).
// ---------------------------------------------------------------------------
template <int XD, int ED2>
__device__ __forceinline__ void conv_layer(
    ushort_t* xsb, ushort_t* esb,          // [16][40], [96][40] bf16 state
    const ushort_t* __restrict__ wq_p, const ushort_t* __restrict__ wk_p,
    const ushort_t* __restrict__ wv_p, const ushort_t* __restrict__ we_p,
    const ushort_t* __restrict__ weo_p,    // global bf16 images
    ushort_t* qb, ushort_t* kb, ushort_t* vb,  // [16][132] bf16
    ushort_t* ehb,                         // [96][132] bf16 (en aliases)
    float* en, float* xn, float* la, int tid)
{
    const int wv_  = tid >> 6;
    const int lane = tid & 63;
    const int l15  = lane & 15;
    const int kg   = lane >> 4;          // k0 = kg*8

    // P1 (merged): q,k (16 tasks) + v (8) + eh (48) = 72 wave-tasks
    for (int task = wv_; task < 72; task += 8) {
        if (task < 16) {
            int mat = task >> 3, nt = task & 7;
            bf16x8 a = *(const bf16x8*)&xsb[l15 * 40 + kg * 8];
            const ushort_t* wp = mat ? wk_p : wq_p;
            bf16x8 bf = *(const bf16x8*)&wp[(nt * 16 + l15) * 40 + kg * 8];
            f32x4 d = {0.f, 0.f, 0.f, 0.f};
            d = __builtin_amdgcn_mfma_f32_16x16x32_bf16(a, bf, d, 0, 0, 0);
            ushort_t* dst = mat ? kb : qb;
            #pragma unroll
            for (int r = 0; r < 4; ++r)
                dst[(kg * 4 + r) * 132 + nt * 16 + l15] = f2b(d[r]);
        } else if (task < 24) {
            int nt = task - 16;
            bf16x8 a = *(const bf16x8*)&xsb[l15 * 40 + kg * 8];
            bf16x8 bf = *(const bf16x8*)&wv_p[(nt * 16 + l15) * 40 + kg * 8];
            f32x4 d = {0.f, 0.f, 0.f, 0.f};
            d = __builtin_amdgcn_mfma_f32_16x16x32_bf16(a, bf, d, 0, 0, 0);
            #pragma unroll
            for (int r = 0; r < 4; ++r)
                vb[(kg * 4 + r) * 132 + nt * 16 + l15] = f2b(d[r]);
        } else {
            int t2 = task - 24, mt = t2 >> 3, nt = t2 & 7;
            bf16x8 a = *(const bf16x8*)&esb[(mt * 16 + l15) * 40 + kg * 8];
            bf16x8 bf = *(const bf16x8*)&we_p[(nt * 16 + l15) * 40 + kg * 8];
            f32x4 d = {0.f, 0.f, 0.f, 0.f};
            d = __builtin_amdgcn_mfma_f32_16x16x32_bf16(a, bf, d, 0, 0, 0);
            #pragma unroll
            for (int r = 0; r < 4; ++r)
                ehb[(mt * 16 + kg * 4 + r) * 132 + nt * 16 + l15] = f2b(d[r]);
        }
    }
    __syncthreads();

    // P2a: logits[le,h] = (q[dst=j] . (k[src=i]+eh)) / sqrt(32)
    for (int idx = tid; idx < 324; idx += TPB) {
        int le = idx >> 2, h = idx & 3;
        int i = le / 9, j = le - i * 9;
        const ushort_t* qp = &qb[j * 132 + h * 32];
        const ushort_t* kp = &kb[i * 132 + h * 32];
        const ushort_t* ep = &ehb[le * 132 + h * 32];
        float acc = 0.f;
        #pragma unroll
        for (int d = 0; d < 32; ++d)
            acc = fmaf(b2f(qp[d]), b2f(kp[d]) + b2f(ep[d]), acc);
        la[idx] = acc * 0.17677669529663687f;
    }
    __syncthreads();

    // P2b: segment softmax over src i per (dst j, head h)
    for (int s = tid; s < 36; s += TPB) {
        int j = s >> 2, h = s & 3;
        float m = -1e30f;
        #pragma unroll
        for (int i = 0; i < 9; ++i) m = fmaxf(m, la[(i * 9 + j) * 4 + h]);
        float ex[9], sum = 0.f;
        #pragma unroll
        for (int i = 0; i < 9; ++i) { ex[i] = __expf(la[(i * 9 + j) * 4 + h] - m); sum += ex[i]; }
        float inv = 1.f / (sum + 1e-16f);
        #pragma unroll
        for (int i = 0; i < 9; ++i) la[(i * 9 + j) * 4 + h] = ex[i] * inv;
    }
    __syncthreads();

    // P3: aggregation -> xn[j,d]  (xn aliases qb; qb dead after P2a)
    for (int idx = tid; idx < 288; idx += TPB) {
        int j = idx >> 5, d = idx & 31;
        float acc = 0.f;
        #pragma unroll
        for (int h = 0; h < 4; ++h)
            #pragma unroll
            for (int i = 0; i < 9; ++i) {
                int le = i * 9 + j;
                acc = fmaf(la[le * 4 + h],
                           b2f(vb[i * 132 + h * 32 + d]) + b2f(ehb[le * 132 + h * 32 + d]), acc);
            }
        xn[idx] = acc * 0.25f;
    }
    __syncthreads();   // ehb reads done (en aliases ehb, written in P4)

    // P4: en = concat(x_src,x_dst,e) @ weo.  A-frags direct from xsb/esb:
    //  layer0 (remapped weo, KS=2): ks0 k<16 -> x_i, k>=16 -> x_j; ks1 -> e
    //  layer1/2 (KS=3): 32-aligned concat -> direct
    const int KS = (XD == 13) ? 2 : 3;
    for (int task = wv_; task < 12; task += 8) {
        int mt = task >> 1, nt = task & 1;
        int le = mt * 16 + l15;
        int i = le / 9, j = le - i * 9;    // le>=81 -> i<=11 (zero xsb rows)
        f32x4 d = {0.f, 0.f, 0.f, 0.f};
        #pragma unroll
        for (int ks = 0; ks < KS; ++ks) {
            bf16x8 a;
            if (XD == 13) {
                if (ks == 0)
                    a = (kg < 2) ? *(const bf16x8*)&xsb[i * 40 + kg * 8]
                                 : *(const bf16x8*)&xsb[j * 40 + (kg - 2) * 8];
                else
                    a = *(const bf16x8*)&esb[le * 40 + kg * 8];
            } else {
                a = (ks == 0) ? *(const bf16x8*)&xsb[i * 40 + kg * 8]
                  : (ks == 1) ? *(const bf16x8*)&xsb[j * 40 + kg * 8]
                              : *(const bf16x8*)&esb[le * 40 + kg * 8];
            }
            bf16x8 bf = *(const bf16x8*)&weo_p[(nt * 16 + l15) * 104 + ks * 32 + kg * 8];
            d = __builtin_amdgcn_mfma_f32_16x16x32_bf16(a, bf, d, 0, 0, 0);
        }
        #pragma unroll
        for (int r = 0; r < 4; ++r) {
            int row = mt * 16 + kg * 4 + r;
            if (row < 81) en[row * 32 + nt * 16 + l15] = d[r];
        }
    }
    __syncthreads();   // xsb/esb reads done before caller overwrites
}

// ---------------------------------------------------------------------------
// Fused GNN.  LDS = 48272 B, VGPR cap 64 via __launch_bounds__(512,4)
// -> targets 2 blocks/CU (16 waves) per the 2xVGPR-shadow occupancy model
// (r17; r10 seated 2 blocks at exactly VGPR 64).  FETCH_SIZE is the spill
// sentinel: if cap 64 forces spills it balloons >100 MB -> revert.
// ---------------------------------------------------------------------------
__global__ __launch_bounds__(TPB, 4) void fused_gnn_kernel(
    const float* __restrict__ nl,    // [B, 117]
    const float* __restrict__ el,    // [B, 405]
    const ushort_t* __restrict__ wb, // precomputed bf16 weight images
    const float* __restrict__ ln0_g, const float* __restrict__ ln0_b,
    const float* __restrict__ ln1_g, const float* __restrict__ ln1_b,
    const float* __restrict__ w_feat, const float* __restrict__ w_eout,
    float* __restrict__ out)
{
    __shared__ __align__(16) ushort_t xsb[16 * 40];     //  1280 B
    __shared__ __align__(16) ushort_t esb[96 * 40];     //  7680 B
    __shared__ __align__(16) ushort_t qb[16 * 132];     //  4224 B (xn aliases)
    __shared__ __align__(16) ushort_t kb[16 * 132];
    __shared__ __align__(16) ushort_t vb[16 * 132];
    __shared__ __align__(16) ushort_t ehb[96 * 132];    // 25344 B (en aliases)
    __shared__ float la[324];                           //  1296 B

    float* en = (float*)ehb;      // [81][32] f32, written P4 (ehb dead)
    float* xn = (float*)qb;       // [9][32] f32, written P3 (qb dead)

    const int b   = blockIdx.x;
    const int tid = threadIdx.x;

    // zero padded state buffers, then stage layer-0 inputs
    for (int idx = tid; idx < 16 * 40; idx += TPB) xsb[idx] = 0;
    for (int idx = tid; idx < 96 * 40; idx += TPB) esb[idx] = 0;
    __syncthreads();
    for (int idx = tid; idx < 117; idx += TPB) {
        int node = idx / 13, m = idx - node * 13;
        xsb[node * 40 + m] = f2b(nl[b * 117 + idx]);
    }
    for (int idx = tid; idx < 405; idx += TPB) {
        int le = idx / 5, c = idx - le * 5;
        int i = le / 9, j = le - i * 9;
        esb[le * 40 + c] = f2b(0.5f * (el[b * 405 + c * 81 + i * 9 + j] +
                                       el[b * 405 + c * 81 + j * 9 + i]));
    }
    __syncthreads();

    for (int layer = 0; layer < 3; ++layer) {
        if (layer == 0)
            conv_layer<13, 5>(xsb, esb,
                              wb + 0, wb + 5120, wb + 10240, wb + 15360, wb + 40960,
                              qb, kb, vb, ehb, en, xn, la, tid);
        else
            conv_layer<32, 32>(xsb, esb,
                               wb + 20480, wb + 25600, wb + 30720, wb + 35840, wb + 44288,
                               qb, kb, vb, ehb, en, xn, la, tid);

        // P5 (layers 0,1): x = leaky(LN(xn)) -> xsb; e = leaky(en) -> esb
        if (layer < 2) {
            const float* g  = (layer == 0) ? ln0_g : ln1_g;
            const float* be = (layer == 0) ? ln0_b : ln1_b;
            for (int idx = tid; idx < 288; idx += TPB) {
                int j = idx >> 5, c = idx & 31;
                float mu = 0.f;
                #pragma unroll
                for (int t = 0; t < 32; ++t) mu += xn[j * 32 + t];
                mu *= (1.f / 32.f);
                float var = 0.f;
                #pragma unroll
                for (int t = 0; t < 32; ++t) { float d = xn[j * 32 + t] - mu; var = fmaf(d, d, var); }
                var *= (1.f / 32.f);
                float val = (xn[idx] - mu) / sqrtf(var + 1e-5f);
                val = val * g[c] + be[c];
                xsb[j * 40 + c] = f2b((val > 0.f) ? val : 0.01f * val);
            }
            for (int idx = tid; idx < 2592; idx += TPB) {
                int le = idx >> 5, c = idx & 31;
                float v = en[idx];
                esb[le * 40 + c] = f2b((v > 0.f) ? v : 0.01f * v);
            }
            __syncthreads();
        }
    }

    // Finals.  After layer 2 (no post): xn [9,32] f32, en [81,32] f32.
    float* out_x  = out;                       // [36864,10]
    float* out_e  = out + 368640;              // [294912,5]
    float* out_ei = out + 1843200;             // [2,294912]
    float* out_b  = out + 2433024;             // [36864]

    for (int idx = tid; idx < 90; idx += TPB) {         // x @ w_feat
        int j = idx / 10, c = idx - j * 10;
        float acc = 0.f;
        #pragma unroll
        for (int kk = 0; kk < 32; ++kk) acc = fmaf(xn[j * 32 + kk], w_feat[kk * 10 + c], acc);
        out_x[(b * 9 + j) * 10 + c] = acc;
    }
    for (int idx = tid; idx < 360; idx += TPB) {        // masked eattr @ w_eout
        int r = idx / 5, c = idx - r * 5;
        int i = r >> 3, jj = r & 7;
        int j = jj + (jj >= i ? 1 : 0);
        const float* row = &en[(i * 9 + j) * 32];
        float acc = 0.f;
        #pragma unroll
        for (int kk = 0; kk < 32; ++kk) acc = fmaf(row[kk], w_eout[kk * 5 + c], acc);
        out_e[(b * 72 + r) * 5 + c] = acc;
    }
    for (int idx = tid; idx < 72; idx += TPB) {         // edge_index
        int i = idx >> 3, jj = idx & 7;
        int j = jj + (jj >= i ? 1 : 0);
        out_ei[b * 72 + idx]          = (float)(b * 9 + i);
        out_ei[294912 + b * 72 + idx] = (float)(b * 9 + j);
    }
    for (int idx = tid; idx < 9; idx += TPB)            // batch
        out_b[b * 9 + idx] = (float)b;
}

// ---------------------------------------------------------------------------
extern "C" void kernel_launch(void* const* d_in, const int* in_sizes, int n_in,
                              void* d_out, int out_size, void* d_ws, size_t ws_size,
                              hipStream_t stream)
{
    const float* latent  = (const float*)d_in[0];
    const float* w_mlp0  = (const float*)d_in[1];
    const float* b_mlp0  = (const float*)d_in[2];
    const float* w_mlp1  = (const float*)d_in[3];
    const float* b_mlp1  = (const float*)d_in[4];
    const float* w_mlp2  = (const float*)d_in[5];
    const float* b_mlp2  = (const float*)d_in[6];
    const float* w_edges = (const float*)d_in[7];
    const float* b_edges = (const float*)d_in[8];
    const float* w_nodes = (const float*)d_in[9];
    const float* b_nodes = (const float*)d_in[10];
    const float* c0_wq   = (const float*)d_in[11];
    const float* c0_wk   = (const float*)d_in[12];
    const float* c0_wv   = (const float*)d_in[13];
    const float* c0_we   = (const float*)d_in[14];
    const float* c0_weo  = (const float*)d_in[15];
    const float* c1_wq   = (const float*)d_in[16];
    const float* c1_wk   = (const float*)d_in[17];
    const float* c1_wv   = (const float*)d_in[18];
    const float* c1_we   = (const float*)d_in[19];
    const float* c1_weo  = (const float*)d_in[20];
    const float* ln0_g   = (const float*)d_in[21];
    const float* ln0_b   = (const float*)d_in[22];
    const float* ln1_g   = (const float*)d_in[23];
    const float* ln1_b   = (const float*)d_in[24];
    const float* w_feat  = (const float*)d_in[25];
    const float* w_eout  = (const float*)d_in[26];

    // Workspace: MLP intermediates (peak 4,804,608 f32 = 18.3 MB) + 95 KB weights
    float* ws = (float*)d_ws;
    float* h0 = ws;
    float* el = ws;
    float* h1 = ws + 1658880;
    float* nl = ws + 1658880;
    float* h2 = ws + 2707456;
    ushort_t* wb = (ushort_t*)(ws + 4804608);   // 47616 ush = 95232 B, 16B-aligned

    float* out = (float*)d_out;

    prep_weights_kernel<<<187, 256, 0, stream>>>(
        c0_wq, c0_wk, c0_wv, c0_we, c0_weo,
        c1_wq, c1_wk, c1_wv, c1_we, c1_weo, wb);

    gemm_tile_kernel<<<256, 256, 0, stream>>>(latent, w_mlp0, b_mlp0, h0, 128, 128, 1);
    gemm_tile_kernel<<<256, 256, 0, stream>>>(h0, w_mlp1, b_mlp1, h1, 128, 256, 1);
    gemm_tile_kernel<<<256, 256, 0, stream>>>(h1, w_mlp2, b_mlp2, h2, 256, 512, 1);
    gemm_tile_kernel<<<256, 256, 0, stream>>>(h2, w_edges, b_edges, el, 512, 405, 0);
    gemm_tile_kernel<<<256, 256, 0, stream>>>(h2, w_nodes, b_nodes, nl, 512, 117, 0);

    fused_gnn_kernel<<<B_, TPB, 0, stream>>>(nl, el, wb,
        ln0_g, ln0_b, ln1_g, ln1_b, w_feat, w_eout, out);
}

// Round 29
// 262.650 us; speedup vs baseline: 5.2432x; 1.6119x over previous
//
#include <hip/hip_runtime.h>
#include <hip/hip_bf16.h>
#include <math.h>

#define B_    4096
#define V_    9
#define N_    (B_*V_)          // 36864 nodes
#define EK_   (B_*V_*(V_-1))   // 294912 kept edges
#define TPB   512

typedef unsigned short ushort_t;
typedef __attribute__((ext_vector_type(8))) short bf16x8;   // 8 bf16 (4 VGPRs)
typedef __attribute__((ext_vector_type(4))) float f32x4;    // 4 f32 acc / 16B chunk

__device__ __forceinline__ float b2f(ushort_t u) {
    union { unsigned int i; float f; } x; x.i = ((unsigned int)u) << 16; return x.f;
}
__device__ __forceinline__ ushort_t f2b(float f) {
    union { float f; unsigned int i; } x; x.f = f;
    unsigned int r = x.i + 0x7FFFu + ((x.i >> 16) & 1u);
    return (ushort_t)(r >> 16);
}

// ---------------------------------------------------------------------------
// MFMA GEMM for the MLP chain: outb[M][Nstride] = act(Ab @ Bt^T + bias), bf16.
// Block 256 thr = 4 waves; tile 128x64; wave w: rows w*32..w*32+32.
// Fragment layouts identical to the PROVEN conv kernel (r21-r28):
//   A: lane l -> row (l&15), k = (l>>4)*8+e   (Ab row-major k-contig)
//   B: lane l -> col (l&15), k = (l>>4)*8+e   (Bt[col][K] k-contig image)
//   D: lane l -> col (l&15), row = (l>>4)*4+r (m89-verified)
// ---------------------------------------------------------------------------
__global__ __launch_bounds__(256) void gemm_mfma_kernel(
    const ushort_t* __restrict__ Ab,   // [M][K] bf16
    const ushort_t* __restrict__ Bt,   // [Npad][K] bf16
    const float* __restrict__ bias,    // [N] f32
    ushort_t* __restrict__ outb,       // [M][Nstride] bf16
    int K, int N, int Nstride, int act, int nblk)
{
    const int bm   = blockIdx.x / nblk;
    const int bn   = blockIdx.x - bm * nblk;
    const int row0 = bm * 128 + (threadIdx.x >> 6) * 32;
    const int n0   = bn * 64;
    const int lane = threadIdx.x & 63;
    const int l15  = lane & 15;
    const int kg   = lane >> 4;

    f32x4 acc[2][4] = {};
    for (int k0 = 0; k0 < K; k0 += 32) {
        bf16x8 a0 = *(const bf16x8*)&Ab[(row0 + l15) * K + k0 + kg * 8];
        bf16x8 a1 = *(const bf16x8*)&Ab[(row0 + 16 + l15) * K + k0 + kg * 8];
        #pragma unroll
        for (int nt = 0; nt < 4; ++nt) {
            bf16x8 bfr = *(const bf16x8*)&Bt[(n0 + nt * 16 + l15) * K + k0 + kg * 8];
            acc[0][nt] = __builtin_amdgcn_mfma_f32_16x16x32_bf16(a0, bfr, acc[0][nt], 0, 0, 0);
            acc[1][nt] = __builtin_amdgcn_mfma_f32_16x16x32_bf16(a1, bfr, acc[1][nt], 0, 0, 0);
        }
    }
    #pragma unroll
    for (int m = 0; m < 2; ++m)
        #pragma unroll
        for (int nt = 0; nt < 4; ++nt) {
            int col = n0 + nt * 16 + l15;
            if (col < N) {
                float bv = bias[col];
                #pragma unroll
                for (int r = 0; r < 4; ++r) {
                    int row = row0 + m * 16 + kg * 4 + r;
                    float v = acc[m][nt][r] + bv;
                    if (act) v = tanhf(v);
                    outb[row * Nstride + col] = f2b(v);
                }
            }
        }
}

// ---------------------------------------------------------------------------
// Conv-weight prep (unchanged from r28).  wb layout (ushort offsets):
//   [0..40960): 8 x [128][40] qkv/e B-images; [40960..47616): 2 x [32][104] weo
// ---------------------------------------------------------------------------
__global__ __launch_bounds__(256) void prep_weights_kernel(
    const float* __restrict__ c0_wq, const float* __restrict__ c0_wk,
    const float* __restrict__ c0_wv, const float* __restrict__ c0_we,
    const float* __restrict__ c0_weo,
    const float* __restrict__ c1_wq, const float* __restrict__ c1_wk,
    const float* __restrict__ c1_wv, const float* __restrict__ c1_we,
    const float* __restrict__ c1_weo,
    ushort_t* __restrict__ wb)
{
    int idx = blockIdx.x * 256 + threadIdx.x;
    if (idx < 40960) {
        int buf = idx / 5120, r = idx - buf * 5120;
        int n = r / 40, m = r - n * 40;
        const float* src; int K;
        switch (buf) {
            case 0: src = c0_wq; K = 13; break;
            case 1: src = c0_wk; K = 13; break;
            case 2: src = c0_wv; K = 13; break;
            case 3: src = c0_we; K = 5;  break;
            case 4: src = c1_wq; K = 32; break;
            case 5: src = c1_wk; K = 32; break;
            case 6: src = c1_wv; K = 32; break;
            default: src = c1_we; K = 32; break;
        }
        wb[idx] = (m < K) ? f2b(src[m * 128 + n]) : (ushort_t)0;
    } else if (idx < 47616) {
        int r2 = idx - 40960;
        int which = r2 / 3328, r = r2 - which * 3328;
        int c = r / 104, row = r - c * 104;
        float v = 0.f;
        if (which) {
            if (row < 96) v = c1_weo[row * 32 + c];
        } else {
            if (row < 13)                    v = c0_weo[row * 32 + c];
            else if (row >= 16 && row < 29)  v = c0_weo[(13 + row - 16) * 32 + c];
            else if (row >= 32 && row < 37)  v = c0_weo[(26 + row - 32) * 32 + c];
        }
        wb[idx] = f2b(v);
    }
}

// ---------------------------------------------------------------------------
// MLP prep: build Bt images for the 5 MLP GEMMs + convert latent to bf16.
// bt layout (ushort offsets within bt): bt0@0 [128][128]; bt1@16384 [256][128];
// bt2@49152 [512][256]; bt3@180224 [448][512] (N=405 zero-padded);
// bt4@409600 [128][512] (N=117 zero-padded).  latb follows at 475136.
// ---------------------------------------------------------------------------
__global__ __launch_bounds__(256) void prep_mlp_kernel(
    const float* __restrict__ w0, const float* __restrict__ w1,
    const float* __restrict__ w2, const float* __restrict__ we,
    const float* __restrict__ wn, const float* __restrict__ latent,
    ushort_t* __restrict__ bt, ushort_t* __restrict__ latb)
{
    int idx = blockIdx.x * 256 + threadIdx.x;
    if (idx < 16384) {                       // L0: K=128, N=128
        int n = idx >> 7, k = idx & 127;
        bt[idx] = f2b(w0[k * 128 + n]);
    } else if (idx < 49152) {                // L1: K=128, N=256
        int r = idx - 16384, n = r >> 7, k = r & 127;
        bt[idx] = f2b(w1[k * 256 + n]);
    } else if (idx < 180224) {               // L2: K=256, N=512
        int r = idx - 49152, n = r >> 8, k = r & 255;
        bt[idx] = f2b(w2[k * 512 + n]);
    } else if (idx < 409600) {               // L3: K=512, N=405 (pad 448)
        int r = idx - 180224, n = r >> 9, k = r & 511;
        bt[idx] = (n < 405) ? f2b(we[k * 405 + n]) : (ushort_t)0;
    } else if (idx < 475136) {               // L4: K=512, N=117 (pad 128)
        int r = idx - 409600, n = r >> 9, k = r & 511;
        bt[idx] = (n < 117) ? f2b(wn[k * 117 + n]) : (ushort_t)0;
    } else if (idx < 999424) {               // latent f32 -> bf16
        int r = idx - 475136;
        latb[r] = f2b(latent[r]);
    }
}

// ---------------------------------------------------------------------------
// MFMA conv layer (math byte-identical to measured r28 winner: 207 us).
// ---------------------------------------------------------------------------
template <int XD, int ED2>
__device__ __forceinline__ void conv_layer(
    ushort_t* xsb, ushort_t* esb,
    const ushort_t* __restrict__ wq_p, const ushort_t* __restrict__ wk_p,
    const ushort_t* __restrict__ wv_p, const ushort_t* __restrict__ we_p,
    const ushort_t* __restrict__ weo_p,
    ushort_t* qb, ushort_t* kb, ushort_t* vb,
    ushort_t* ehb, float* en, float* xn, float* la, int tid)
{
    const int wv_  = tid >> 6;
    const int lane = tid & 63;
    const int l15  = lane & 15;
    const int kg   = lane >> 4;

    // P1 (merged): q,k (16 tasks) + v (8) + eh (48) = 72 wave-tasks
    for (int task = wv_; task < 72; task += 8) {
        if (task < 16) {
            int mat = task >> 3, nt = task & 7;
            bf16x8 a = *(const bf16x8*)&xsb[l15 * 40 + kg * 8];
            const ushort_t* wp = mat ? wk_p : wq_p;
            bf16x8 bf = *(const bf16x8*)&wp[(nt * 16 + l15) * 40 + kg * 8];
            f32x4 d = {0.f, 0.f, 0.f, 0.f};
            d = __builtin_amdgcn_mfma_f32_16x16x32_bf16(a, bf, d, 0, 0, 0);
            ushort_t* dst = mat ? kb : qb;
            #pragma unroll
            for (int r = 0; r < 4; ++r)
                dst[(kg * 4 + r) * 132 + nt * 16 + l15] = f2b(d[r]);
        } else if (task < 24) {
            int nt = task - 16;
            bf16x8 a = *(const bf16x8*)&xsb[l15 * 40 + kg * 8];
            bf16x8 bf = *(const bf16x8*)&wv_p[(nt * 16 + l15) * 40 + kg * 8];
            f32x4 d = {0.f, 0.f, 0.f, 0.f};
            d = __builtin_amdgcn_mfma_f32_16x16x32_bf16(a, bf, d, 0, 0, 0);
            #pragma unroll
            for (int r = 0; r < 4; ++r)
                vb[(kg * 4 + r) * 132 + nt * 16 + l15] = f2b(d[r]);
        } else {
            int t2 = task - 24, mt = t2 >> 3, nt = t2 & 7;
            bf16x8 a = *(const bf16x8*)&esb[(mt * 16 + l15) * 40 + kg * 8];
            bf16x8 bf = *(const bf16x8*)&we_p[(nt * 16 + l15) * 40 + kg * 8];
            f32x4 d = {0.f, 0.f, 0.f, 0.f};
            d = __builtin_amdgcn_mfma_f32_16x16x32_bf16(a, bf, d, 0, 0, 0);
            #pragma unroll
            for (int r = 0; r < 4; ++r)
                ehb[(mt * 16 + kg * 4 + r) * 132 + nt * 16 + l15] = f2b(d[r]);
        }
    }
    __syncthreads();

    // P2a: logits
    for (int idx = tid; idx < 324; idx += TPB) {
        int le = idx >> 2, h = idx & 3;
        int i = le / 9, j = le - i * 9;
        const ushort_t* qp = &qb[j * 132 + h * 32];
        const ushort_t* kp = &kb[i * 132 + h * 32];
        const ushort_t* ep = &ehb[le * 132 + h * 32];
        float acc = 0.f;
        #pragma unroll
        for (int d = 0; d < 32; ++d)
            acc = fmaf(b2f(qp[d]), b2f(kp[d]) + b2f(ep[d]), acc);
        la[idx] = acc * 0.17677669529663687f;
    }
    __syncthreads();

    // P2b: segment softmax
    for (int s = tid; s < 36; s += TPB) {
        int j = s >> 2, h = s & 3;
        float m = -1e30f;
        #pragma unroll
        for (int i = 0; i < 9; ++i) m = fmaxf(m, la[(i * 9 + j) * 4 + h]);
        float ex[9], sum = 0.f;
        #pragma unroll
        for (int i = 0; i < 9; ++i) { ex[i] = __expf(la[(i * 9 + j) * 4 + h] - m); sum += ex[i]; }
        float inv = 1.f / (sum + 1e-16f);
        #pragma unroll
        for (int i = 0; i < 9; ++i) la[(i * 9 + j) * 4 + h] = ex[i] * inv;
    }
    __syncthreads();

    // P3: aggregation -> xn (aliases qb)
    for (int idx = tid; idx < 288; idx += TPB) {
        int j = idx >> 5, d = idx & 31;
        float acc = 0.f;
        #pragma unroll
        for (int h = 0; h < 4; ++h)
            #pragma unroll
            for (int i = 0; i < 9; ++i) {
                int le = i * 9 + j;
                acc = fmaf(la[le * 4 + h],
                           b2f(vb[i * 132 + h * 32 + d]) + b2f(ehb[le * 132 + h * 32 + d]), acc);
            }
        xn[idx] = acc * 0.25f;
    }
    __syncthreads();

    // P4: edge-MLP, A-frags direct from xsb/esb
    const int KS = (XD == 13) ? 2 : 3;
    for (int task = wv_; task < 12; task += 8) {
        int mt = task >> 1, nt = task & 1;
        int le = mt * 16 + l15;
        int i = le / 9, j = le - i * 9;
        f32x4 d = {0.f, 0.f, 0.f, 0.f};
        #pragma unroll
        for (int ks = 0; ks < KS; ++ks) {
            bf16x8 a;
            if (XD == 13) {
                if (ks == 0)
                    a = (kg < 2) ? *(const bf16x8*)&xsb[i * 40 + kg * 8]
                                 : *(const bf16x8*)&xsb[j * 40 + (kg - 2) * 8];
                else
                    a = *(const bf16x8*)&esb[le * 40 + kg * 8];
            } else {
                a = (ks == 0) ? *(const bf16x8*)&xsb[i * 40 + kg * 8]
                  : (ks == 1) ? *(const bf16x8*)&xsb[j * 40 + kg * 8]
                              : *(const bf16x8*)&esb[le * 40 + kg * 8];
            }
            bf16x8 bf = *(const bf16x8*)&weo_p[(nt * 16 + l15) * 104 + ks * 32 + kg * 8];
            d = __builtin_amdgcn_mfma_f32_16x16x32_bf16(a, bf, d, 0, 0, 0);
        }
        #pragma unroll
        for (int r = 0; r < 4; ++r) {
            int row = mt * 16 + kg * 4 + r;
            if (row < 81) en[row * 32 + nt * 16 + l15] = d[r];
        }
    }
    __syncthreads();
}

// ---------------------------------------------------------------------------
// Fused GNN (r28 winner; only input staging changed to bf16 nlb/elb).
// ---------------------------------------------------------------------------
__global__ __launch_bounds__(TPB, 4) void fused_gnn_kernel(
    const ushort_t* __restrict__ nlb,  // [B][120] bf16 (117 used)
    const ushort_t* __restrict__ elb,  // [B][408] bf16 (405 used)
    const ushort_t* __restrict__ wb,
    const float* __restrict__ ln0_g, const float* __restrict__ ln0_b,
    const float* __restrict__ ln1_g, const float* __restrict__ ln1_b,
    const float* __restrict__ w_feat, const float* __restrict__ w_eout,
    float* __restrict__ out)
{
    __shared__ __align__(16) ushort_t xsb[16 * 40];
    __shared__ __align__(16) ushort_t esb[96 * 40];
    __shared__ __align__(16) ushort_t qb[16 * 132];
    __shared__ __align__(16) ushort_t kb[16 * 132];
    __shared__ __align__(16) ushort_t vb[16 * 132];
    __shared__ __align__(16) ushort_t ehb[96 * 132];
    __shared__ float la[324];

    float* en = (float*)ehb;
    float* xn = (float*)qb;

    const int b   = blockIdx.x;
    const int tid = threadIdx.x;

    for (int idx = tid; idx < 16 * 40; idx += TPB) xsb[idx] = 0;
    for (int idx = tid; idx < 96 * 40; idx += TPB) esb[idx] = 0;
    __syncthreads();
    for (int idx = tid; idx < 117; idx += TPB) {
        int node = idx / 13, m = idx - node * 13;
        xsb[node * 40 + m] = nlb[b * 120 + idx];
    }
    for (int idx = tid; idx < 405; idx += TPB) {
        int le = idx / 5, c = idx - le * 5;
        int i = le / 9, j = le - i * 9;
        esb[le * 40 + c] = f2b(0.5f * (b2f(elb[b * 408 + c * 81 + i * 9 + j]) +
                                       b2f(elb[b * 408 + c * 81 + j * 9 + i])));
    }
    __syncthreads();

    for (int layer = 0; layer < 3; ++layer) {
        if (layer == 0)
            conv_layer<13, 5>(xsb, esb,
                              wb + 0, wb + 5120, wb + 10240, wb + 15360, wb + 40960,
                              qb, kb, vb, ehb, en, xn, la, tid);
        else
            conv_layer<32, 32>(xsb, esb,
                               wb + 20480, wb + 25600, wb + 30720, wb + 35840, wb + 44288,
                               qb, kb, vb, ehb, en, xn, la, tid);

        if (layer < 2) {
            const float* g  = (layer == 0) ? ln0_g : ln1_g;
            const float* be = (layer == 0) ? ln0_b : ln1_b;
            for (int idx = tid; idx < 288; idx += TPB) {
                int j = idx >> 5, c = idx & 31;
                float mu = 0.f;
                #pragma unroll
                for (int t = 0; t < 32; ++t) mu += xn[j * 32 + t];
                mu *= (1.f / 32.f);
                float var = 0.f;
                #pragma unroll
                for (int t = 0; t < 32; ++t) { float d = xn[j * 32 + t] - mu; var = fmaf(d, d, var); }
                var *= (1.f / 32.f);
                float val = (xn[idx] - mu) / sqrtf(var + 1e-5f);
                val = val * g[c] + be[c];
                xsb[j * 40 + c] = f2b((val > 0.f) ? val : 0.01f * val);
            }
            for (int idx = tid; idx < 2592; idx += TPB) {
                int le = idx >> 5, c = idx & 31;
                float v = en[idx];
                esb[le * 40 + c] = f2b((v > 0.f) ? v : 0.01f * v);
            }
            __syncthreads();
        }
    }

    float* out_x  = out;                       // [36864,10]
    float* out_e  = out + 368640;              // [294912,5]
    float* out_ei = out + 1843200;             // [2,294912]
    float* out_b  = out + 2433024;             // [36864]

    for (int idx = tid; idx < 90; idx += TPB) {
        int j = idx / 10, c = idx - j * 10;
        float acc = 0.f;
        #pragma unroll
        for (int kk = 0; kk < 32; ++kk) acc = fmaf(xn[j * 32 + kk], w_feat[kk * 10 + c], acc);
        out_x[(b * 9 + j) * 10 + c] = acc;
    }
    for (int idx = tid; idx < 360; idx += TPB) {
        int r = idx / 5, c = idx - r * 5;
        int i = r >> 3, jj = r & 7;
        int j = jj + (jj >= i ? 1 : 0);
        const float* row = &en[(i * 9 + j) * 32];
        float acc = 0.f;
        #pragma unroll
        for (int kk = 0; kk < 32; ++kk) acc = fmaf(row[kk], w_eout[kk * 5 + c], acc);
        out_e[(b * 72 + r) * 5 + c] = acc;
    }
    for (int idx = tid; idx < 72; idx += TPB) {
        int i = idx >> 3, jj = idx & 7;
        int j = jj + (jj >= i ? 1 : 0);
        out_ei[b * 72 + idx]          = (float)(b * 9 + i);
        out_ei[294912 + b * 72 + idx] = (float)(b * 9 + j);
    }
    for (int idx = tid; idx < 9; idx += TPB)
        out_b[b * 9 + idx] = (float)b;
}

// ---------------------------------------------------------------------------
extern "C" void kernel_launch(void* const* d_in, const int* in_sizes, int n_in,
                              void* d_out, int out_size, void* d_ws, size_t ws_size,
                              hipStream_t stream)
{
    const float* latent  = (const float*)d_in[0];
    const float* w_mlp0  = (const float*)d_in[1];
    const float* b_mlp0  = (const float*)d_in[2];
    const float* w_mlp1  = (const float*)d_in[3];
    const float* b_mlp1  = (const float*)d_in[4];
    const float* w_mlp2  = (const float*)d_in[5];
    const float* b_mlp2  = (const float*)d_in[6];
    const float* w_edges = (const float*)d_in[7];
    const float* b_edges = (const float*)d_in[8];
    const float* w_nodes = (const float*)d_in[9];
    const float* b_nodes = (const float*)d_in[10];
    const float* c0_wq   = (const float*)d_in[11];
    const float* c0_wk   = (const float*)d_in[12];
    const float* c0_wv   = (const float*)d_in[13];
    const float* c0_we   = (const float*)d_in[14];
    const float* c0_weo  = (const float*)d_in[15];
    const float* c1_wq   = (const float*)d_in[16];
    const float* c1_wk   = (const float*)d_in[17];
    const float* c1_wv   = (const float*)d_in[18];
    const float* c1_we   = (const float*)d_in[19];
    const float* c1_weo  = (const float*)d_in[20];
    const float* ln0_g   = (const float*)d_in[21];
    const float* ln0_b   = (const float*)d_in[22];
    const float* ln1_g   = (const float*)d_in[23];
    const float* ln1_b   = (const float*)d_in[24];
    const float* w_feat  = (const float*)d_in[25];
    const float* w_eout  = (const float*)d_in[26];

    // Workspace layout (ushort offsets; all 16B-aligned):
    //   wb   [0       .. 47616)    conv weight images
    //   bt   [47616   .. 522752)   MLP Bt images
    //   latb [522752  .. 1047040)  latent bf16 [4096][128]
    //   h0b  [1047040 .. 1571328)  [4096][128]
    //   h1b  [1571328 .. 2619904)  [4096][256]
    //   h2b  [2619904 .. 4717056)  [4096][512]
    //   elb  [4717056 .. 6388224)  [4096][408] (405 used)
    //   nlb  [6388224 .. 6879744)  [4096][120] (117 used)
    ushort_t* wsu  = (ushort_t*)d_ws;
    ushort_t* wb   = wsu;
    ushort_t* bt   = wsu + 47616;
    ushort_t* latb = wsu + 522752;
    ushort_t* h0b  = wsu + 1047040;
    ushort_t* h1b  = wsu + 1571328;
    ushort_t* h2b  = wsu + 2619904;
    ushort_t* elb  = wsu + 4717056;
    ushort_t* nlb  = wsu + 6388224;

    float* out = (float*)d_out;

    prep_weights_kernel<<<187, 256, 0, stream>>>(
        c0_wq, c0_wk, c0_wv, c0_we, c0_weo,
        c1_wq, c1_wk, c1_wv, c1_we, c1_weo, wb);
    prep_mlp_kernel<<<3904, 256, 0, stream>>>(
        w_mlp0, w_mlp1, w_mlp2, w_edges, w_nodes, latent, bt, latb);

    // MLP chain on MFMA (M=4096; bm blocks = 32)
    gemm_mfma_kernel<<<32 * 2, 256, 0, stream>>>(latb, bt + 0,      b_mlp0, h0b, 128, 128, 128, 1, 2);
    gemm_mfma_kernel<<<32 * 4, 256, 0, stream>>>(h0b,  bt + 16384,  b_mlp1, h1b, 128, 256, 256, 1, 4);
    gemm_mfma_kernel<<<32 * 8, 256, 0, stream>>>(h1b,  bt + 49152,  b_mlp2, h2b, 256, 512, 512, 1, 8);
    gemm_mfma_kernel<<<32 * 7, 256, 0, stream>>>(h2b,  bt + 180224, b_edges, elb, 512, 405, 408, 0, 7);
    gemm_mfma_kernel<<<32 * 2, 256, 0, stream>>>(h2b,  bt + 409600, b_nodes, nlb, 512, 117, 120, 0, 2);

    fused_gnn_kernel<<<B_, TPB, 0, stream>>>(nlb, elb, wb,
        ln0_g, ln0_b, ln1_g, ln1_b, w_feat, w_eout, out);
}